// Round 19
// baseline (195.189 us; speedup 1.0000x reference)
//
#include <hip/hip_runtime.h>

namespace {

typedef unsigned short u16;
typedef __bf16 bf16x8 __attribute__((ext_vector_type(8)));
typedef __bf16 bf16x2 __attribute__((ext_vector_type(2)));
typedef float f32x4 __attribute__((ext_vector_type(4)));
typedef float f32x16 __attribute__((ext_vector_type(16)));
typedef u16 u16x8v __attribute__((ext_vector_type(8)));
struct alignas(8) u16x4 { u16 x, y, z, w; };
union U32x4 { unsigned int u[4]; bf16x8 v; };

constexpr int kS    = 4096;
constexpr int kE    = 768;
constexpr int kH    = 12;
constexpr int kD    = 64;
constexpr int kQKV  = 2304;   // 3*E
constexpr int kChunk = 256;
constexpr int kC    = 16;     // S / CHUNK
constexpr int kB    = 2;
constexpr float kScale = 0.125f;  // 1/sqrt(64)
constexpr int kRowB = 9216;       // qkv row bytes
constexpr int kClsSplit = 16;     // key-chunks per (b,h) for CLS attention
constexpr float kL2 = 0.83048202372184058696f;  // log2(10000)/16

// ---- bf16 helpers (RNE) ---------------------------------------------------
__device__ __forceinline__ u16 f2bf(float f) {
  unsigned int u = __float_as_uint(f);
  u += 0x7FFFu + ((u >> 16) & 1u);
  return (u16)(u >> 16);
}
__device__ __forceinline__ float bf2f(u16 h) {
  return __uint_as_float(((unsigned int)h) << 16);
}
// packed pair via casts -> v_cvt_pk_bf16_f32 (RNE, same bits as f2bf here)
__device__ __forceinline__ unsigned int pkbf(float a, float b) {
  bf16x2 p;
  p[0] = (__bf16)a;
  p[1] = (__bf16)b;
  return __builtin_bit_cast(unsigned int, p);
}

// ---- XCD-aware bijective block swizzle (grid % 8 == 0) ---------------------
__device__ __forceinline__ int xcd_swz(int bid, int nwg) {
  const int cpx = nwg >> 3;
  return (bid & 7) * cpx + (bid >> 3);
}

// ---- async global->LDS, 16B per lane --------------------------------------
__device__ __forceinline__ void glds16(const void* g, void* l) {
  __builtin_amdgcn_global_load_lds(
      (const __attribute__((address_space(1))) unsigned int*)g,
      (__attribute__((address_space(3))) unsigned int*)l, 16, 0, 0);
}

// ---------------------------------------------------------------------------
// wsplit body: W[K][N] fp32 -> Th[N][K] bf16 (transposed, hi only).
// ---------------------------------------------------------------------------
__device__ __forceinline__ void wsplit_body(const float* __restrict__ W,
                                            u16* __restrict__ Th, int K, int N,
                                            int bid, int t, float (*tile)[65]) {
  const int ntiles = N >> 6;
  const int n0 = (bid % ntiles) << 6;
  const int k0 = (bid / ntiles) << 6;
  const int r  = t >> 2;
  const int cs = (t & 3) << 4;
  const float* src = W + (size_t)(k0 + r) * N + n0 + cs;
#pragma unroll
  for (int i = 0; i < 4; ++i) {
    float4 v = *(const float4*)(src + 4 * i);
    tile[r][cs + 4 * i + 0] = v.x;
    tile[r][cs + 4 * i + 1] = v.y;
    tile[r][cs + 4 * i + 2] = v.z;
    tile[r][cs + 4 * i + 3] = v.w;
  }
  __syncthreads();
  u16* dh = Th + (size_t)(n0 + r) * K + k0 + cs;
#pragma unroll
  for (int i = 0; i < 4; ++i) {
    u16x4 hq;
    hq.x = f2bf(tile[cs + 4 * i + 0][r]);
    hq.y = f2bf(tile[cs + 4 * i + 1][r]);
    hq.z = f2bf(tile[cs + 4 * i + 2][r]);
    hq.w = f2bf(tile[cs + 4 * i + 3][r]);
    *(u16x4*)(dh + 4 * i) = hq;
  }
}

// ---------------------------------------------------------------------------
// wsplit_q: transpose+bf16 W_qkv (432 blocks).
// ---------------------------------------------------------------------------
__global__ __launch_bounds__(256)
void wsplit_q(const float* __restrict__ Wq, u16* __restrict__ WqTh) {
  __shared__ float tile[64][65];
  wsplit_body(Wq, WqTh, kE, kQKV, blockIdx.x, threadIdx.x, tile);
}

// ---------------------------------------------------------------------------
// tail: blocks [0,144) = wsplit(W_out); blocks [144,168) = cls combine.
// ---------------------------------------------------------------------------
__global__ __launch_bounds__(256)
void wsplit_comb(const float* __restrict__ Wout, u16* __restrict__ WoTh,
                 const float* __restrict__ part,
                 u16* __restrict__ oh, u16* __restrict__ ol) {
  __shared__ float tile[64][65];
  if (blockIdx.x < 144) {
    wsplit_body(Wout, WoTh, kE, kE, blockIdx.x, threadIdx.x, tile);
  } else {
    if (threadIdx.x >= 64) return;
    const int bid = blockIdx.x - 144;      // 0..23
    const int h = bid % kH;
    const int b = bid / kH;
    const int lane = threadIdx.x;
    const float* src = part + (size_t)((b * kH + h) * kClsSplit) * 66;
    float s = 0.f, L = 0.f;
#pragma unroll
    for (int p = 0; p < kClsSplit; ++p) {
      s += src[p * 66 + lane];
      L += src[p * 66 + 64];
    }
    const float v = s / L;
    const u16 hb = f2bf(v);
    const size_t off0 = (size_t)(b * kS) * kE + h * kD + lane;
    oh[off0] = hb;
    ol[off0] = f2bf(v - bf2f(hb));
  }
}

// ---------------------------------------------------------------------------
// QKV GEMM: A = x fp32 (split in-kernel, r9-proven staging), B = WqTh bf16.
// 128x128 tile, 2-term (Ah@Bh + Al@Bh), single-buffer LDS (34 KB), plain
// __syncthreads barrier pair, fused rope/pack/V^T epilogue (r14-proven).
// ---------------------------------------------------------------------------
__global__ __launch_bounds__(256, 2)
void gemm_qkv(const float* __restrict__ x, const u16* __restrict__ Bhg,
              const float* __restrict__ bias, char* __restrict__ outPk,
              const int* __restrict__ coords, int M, int N, int K) {
  // [AsH 4096 | AsL 4096 | BsH 4096] u16 staging; epilogue ldsT reuses
  // smem[0 .. 17408) (4 waves x 64x68 u16) after the final sync.
  __shared__ __align__(16) u16 smem[17408];
  u16* AsH = smem;
  u16* AsL = smem + 4096;
  u16* BsH = smem + 8192;

  const int nwg = gridDim.x;
  const int lid = xcd_swz(blockIdx.x, nwg);
  const int nTiles = N >> 7;
  const int m0 = (lid / nTiles) << 7;
  const int n0 = (lid % nTiles) << 7;

  const int tid  = threadIdx.x;
  const int wave = tid >> 6;
  const int lane = tid & 63;
  const int l15  = lane & 15;
  const int khf  = lane >> 4;
  const int wm   = wave >> 1;
  const int wn   = wave & 1;

  const int c0 = wave * 2, c1 = wave * 2 + 1;
  const int rr = lane >> 2;
  const int gg = lane & 3;

  const size_t bOff0 = (size_t)(n0 + c0 * 16 + rr) * K + gg * 8;
  const size_t bOff1 = (size_t)(n0 + c1 * 16 + rr) * K + gg * 8;

  // A fp32 in-kernel staging indices (r9-proven)
  const int am  = tid >> 1;           // 0..127
  const int aks = (tid & 1) * 16;     // 0 or 16
  const float* aP = x + (size_t)(m0 + am) * K + aks;

  f32x4 acc[4][4];
#pragma unroll
  for (int i = 0; i < 4; ++i)
#pragma unroll
    for (int j = 0; j < 4; ++j) acc[i][j] = (f32x4){0.f, 0.f, 0.f, 0.f};

  for (int k0 = 0; k0 < K; k0 += 32) {
    float a[16];
    {
      const float4 v0 = *(const float4*)(aP + k0 + 0);
      const float4 v1 = *(const float4*)(aP + k0 + 4);
      const float4 v2 = *(const float4*)(aP + k0 + 8);
      const float4 v3 = *(const float4*)(aP + k0 + 12);
      a[0] = v0.x; a[1] = v0.y; a[2]  = v0.z; a[3]  = v0.w;
      a[4] = v1.x; a[5] = v1.y; a[6]  = v1.z; a[7]  = v1.w;
      a[8] = v2.x; a[9] = v2.y; a[10] = v2.z; a[11] = v2.w;
      a[12] = v3.x; a[13] = v3.y; a[14] = v3.z; a[15] = v3.w;
    }
    __syncthreads();   // previous iteration's frag reads complete

    glds16(Bhg + bOff0 + k0, BsH + (c0 * 16) * 32);
    glds16(Bhg + bOff1 + k0, BsH + (c1 * 16) * 32);
#pragma unroll
    for (int i = 0; i < 4; ++i) {
      u16x4 hq, lq;
      float f;
      f = a[4 * i + 0]; hq.x = f2bf(f); lq.x = f2bf(f - bf2f(hq.x));
      f = a[4 * i + 1]; hq.y = f2bf(f); lq.y = f2bf(f - bf2f(hq.y));
      f = a[4 * i + 2]; hq.z = f2bf(f); lq.z = f2bf(f - bf2f(hq.z));
      f = a[4 * i + 3]; hq.w = f2bf(f); lq.w = f2bf(f - bf2f(hq.w));
      *(u16x4*)&AsH[am * 32 + aks + 4 * i] = hq;
      *(u16x4*)&AsL[am * 32 + aks + 4 * i] = lq;
    }
    __syncthreads();   // drains vmcnt (glds) + lgkmcnt (ds_write)

    bf16x8 fah[4], fal[4], fbh[4];
#pragma unroll
    for (int f = 0; f < 4; ++f) {
      fah[f] = *(const bf16x8*)&AsH[(wm * 64 + f * 16 + l15) * 32 + khf * 8];
      fal[f] = *(const bf16x8*)&AsL[(wm * 64 + f * 16 + l15) * 32 + khf * 8];
      fbh[f] = *(const bf16x8*)&BsH[(wn * 64 + f * 16 + l15) * 32 + khf * 8];
    }
#pragma unroll
    for (int mi = 0; mi < 4; ++mi)
#pragma unroll
      for (int ni = 0; ni < 4; ++ni)
        acc[mi][ni] = __builtin_amdgcn_mfma_f32_16x16x32_bf16(fah[mi], fbh[ni], acc[mi][ni], 0, 0, 0);
#pragma unroll
    for (int mi = 0; mi < 4; ++mi)
#pragma unroll
      for (int ni = 0; ni < 4; ++ni)
        acc[mi][ni] = __builtin_amdgcn_mfma_f32_16x16x32_bf16(fal[mi], fbh[ni], acc[mi][ni], 0, 0, 0);
  }

  // ---- fused epilogue (r14-proven): rope/pack q,k; bf16 + V^T for v ----
  __syncthreads();   // all LDS staging reads done; smem free for bounce

  const int col64  = (n0 >> 6) + wn;   // 0..35
  const int sector = col64 / 12;       // 0=q, 1=k, 2=v
  const int hh     = col64 % 12;
  const int rowbase = m0 + wm * 64;    // 64-aligned

  if (sector < 2) {
    const int sel = sector;
#pragma unroll
    for (int mi = 0; mi < 4; ++mi)
#pragma unroll
      for (int r = 0; r < 4; ++r) {
        const int row = rowbase + mi * 16 + khf * 4 + r;
        const int bb = row >> 12;
        const int ss = row & 4095;
        float cx = 0.f, cy = 0.f;
        if (ss >= 1) {
          const size_t ci = ((size_t)bb * (kS - 1) + (ss - 1)) * 2;
          cx = (float)coords[ci]     * (1.0f / 100000.0f);
          cy = (float)coords[ci + 1] * (1.0f / 100000.0f);
        }
        const int swz = (sel == 1) ? (ss & 7) : 0;
        char* base = outPk + (size_t)row * kRowB + sel * 3072 + hh * 256;
#pragma unroll
        for (int ni = 0; ni < 4; ++ni) {
          const int d = ni * 16 + l15;
          const float v0 = acc[mi][ni][r] + bias[n0 + wn * 64 + ni * 16 + l15];
          const float pv = __shfl_xor(v0, 1);   // partner d^1 (all lanes exec)
          float nv = v0;
          if (ss >= 1) {
            const float coord = (d < 32) ? cx : cy;
            const float ang = coord * exp2f(-(float)((d >> 1) & 15) * kL2);
            const float sn = __sinf(ang), cn = __cosf(ang);
            nv = (d & 1) ? fmaf(v0, cn, pv * sn) : fmaf(v0, cn, -pv * sn);
          }
          const u16 hb = f2bf(nv);
          const u16 lb = f2bf(nv - bf2f(hb));
          const int gofs = (((d >> 3) ^ swz) << 4) + (d & 7) * 2;
          *(u16*)(base + gofs) = hb;
          *(u16*)(base + 128 + gofs) = lb;
        }
      }
  } else {
    u16* ldsT = smem + wave * 4352;    // 64 x 68 u16 per wave (8.5 KB)
#pragma unroll
    for (int mi = 0; mi < 4; ++mi)
#pragma unroll
      for (int ni = 0; ni < 4; ++ni)
#pragma unroll
        for (int r = 0; r < 4; ++r) {
          const int key = mi * 16 + khf * 4 + r;   // row within 64-group
          const int row = rowbase + key;
          const int d = ni * 16 + l15;
          const float v0 = acc[mi][ni][r] + bias[n0 + wn * 64 + ni * 16 + l15];
          const u16 hb = f2bf(v0);
          *(u16*)(outPk + (size_t)row * kRowB + 6144 + hh * 256 + d * 2) = hb;
          ldsT[d * 68 + key] = hb;
        }
    const int dd = lane;               // V^T row = d
    char* vbase = outPk + (size_t)(rowbase + dd) * kRowB + 6144 + hh * 256 + 128;
#pragma unroll
    for (int kgx = 0; kgx < 8; ++kgx) {
      const u16x4 a0 = *(const u16x4*)&ldsT[dd * 68 + kgx * 8];
      const u16x4 a1 = *(const u16x4*)&ldsT[dd * 68 + kgx * 8 + 4];
      char* dst = vbase + ((kgx ^ (dd & 7)) << 4);
      *(u16x4*)dst = a0;
      *(u16x4*)(dst + 8) = a1;
    }
  }
}

// ---------------------------------------------------------------------------
// Thin GEMM for out-projection (round-17, unchanged): 64x128 tile, depth-2
// pipelined, LDS group-XOR swizzle.
// ---------------------------------------------------------------------------
__global__ __launch_bounds__(256, 2)
void gemm_thin(const u16* __restrict__ Ahg, const u16* __restrict__ Alg,
               const u16* __restrict__ Bhg,
               const float* __restrict__ bias, float* __restrict__ C,
               int M, int N, int K) {
  __shared__ __align__(16) u16 smem[16384];   // 2 x (Ah 2048 | Al 2048 | B 4096)
  const int nwg = gridDim.x;
  const int lid = xcd_swz(blockIdx.x, nwg);
  const int nTiles = N >> 7;
  const int m0 = (lid / nTiles) << 6;
  const int n0 = (lid % nTiles) << 7;

  const int tid  = threadIdx.x;
  const int wave = tid >> 6;
  const int lane = tid & 63;
  const int l15  = lane & 15;
  const int khf  = lane >> 4;

  const int rr = lane >> 2;
  const int gg = lane & 3;
  const int gsw = gg ^ ((rr >> 1) & 3);
  const int kg  = khf ^ ((l15 >> 1) & 3);

  const size_t aOff  = (size_t)(m0 + wave * 16 + rr) * K + gsw * 8;
  const size_t bOff0 = (size_t)(n0 + (2 * wave) * 16 + rr) * K + gsw * 8;
  const size_t bOff1 = (size_t)(n0 + (2 * wave + 1) * 16 + rr) * K + gsw * 8;

  auto STAGE = [&](int p, int k0) {
    u16* base = smem + p * 8192;
    glds16(Ahg + aOff + k0,  base + (wave * 16) * 32);
    glds16(Alg + aOff + k0,  base + 2048 + (wave * 16) * 32);
    glds16(Bhg + bOff0 + k0, base + 4096 + (2 * wave * 16) * 32);
    glds16(Bhg + bOff1 + k0, base + 4096 + ((2 * wave + 1) * 16) * 32);
  };

  f32x4 acc[4][2];
#pragma unroll
  for (int i = 0; i < 4; ++i)
#pragma unroll
    for (int j = 0; j < 2; ++j) acc[i][j] = (f32x4){0.f, 0.f, 0.f, 0.f};

  auto COMPUTE = [&](int p) {
    u16* base = smem + p * 8192;
    bf16x8 fah[4], fal[4], fbh[2];
#pragma unroll
    for (int f = 0; f < 4; ++f) {
      fah[f] = *(const bf16x8*)&base[(f * 16 + l15) * 32 + kg * 8];
      fal[f] = *(const bf16x8*)&base[2048 + (f * 16 + l15) * 32 + kg * 8];
    }
#pragma unroll
    for (int f = 0; f < 2; ++f)
      fbh[f] = *(const bf16x8*)&base[4096 + (wave * 32 + f * 16 + l15) * 32 + kg * 8];
#pragma unroll
    for (int mi = 0; mi < 4; ++mi)
#pragma unroll
      for (int ni = 0; ni < 2; ++ni)
        acc[mi][ni] = __builtin_amdgcn_mfma_f32_16x16x32_bf16(fah[mi], fbh[ni], acc[mi][ni], 0, 0, 0);
#pragma unroll
    for (int mi = 0; mi < 4; ++mi)
#pragma unroll
      for (int ni = 0; ni < 2; ++ni)
        acc[mi][ni] = __builtin_amdgcn_mfma_f32_16x16x32_bf16(fal[mi], fbh[ni], acc[mi][ni], 0, 0, 0);
  };

  STAGE(0, 0);
  STAGE(1, 32);
  int cur = 0;

  for (int k0 = 0; k0 < K - 32; k0 += 32) {
    asm volatile("s_waitcnt vmcnt(4)" ::: "memory");
    __builtin_amdgcn_sched_barrier(0);
    __builtin_amdgcn_s_barrier();

    COMPUTE(cur);

    __builtin_amdgcn_sched_barrier(0);
    asm volatile("s_waitcnt lgkmcnt(0)" ::: "memory");
    __builtin_amdgcn_s_barrier();
    if (k0 + 64 < K) STAGE(cur, k0 + 64);
    cur ^= 1;
  }

  asm volatile("s_waitcnt vmcnt(0)" ::: "memory");
  __builtin_amdgcn_sched_barrier(0);
  __builtin_amdgcn_s_barrier();
  COMPUTE(cur);

#pragma unroll
  for (int ni = 0; ni < 2; ++ni) {
    const int col = n0 + wave * 32 + ni * 16 + l15;
    const float bv = bias[col];
#pragma unroll
    for (int mi = 0; mi < 4; ++mi) {
      const int rbase = m0 + mi * 16 + khf * 4;
#pragma unroll
      for (int r = 0; r < 4; ++r)
        C[(size_t)(rbase + r) * N + col] = acc[mi][ni][r] + bv;
    }
  }
}

// ---------------------------------------------------------------------------
// Windowed attention + fused CLS partials (round-18, unchanged).
// Grid = 768 attn + 192 cls = 960; LDS 24.5 KB.
// ---------------------------------------------------------------------------
__global__ __launch_bounds__(128)
void attn_win_mfma(const char* __restrict__ qkvB,
                   u16* __restrict__ oh, u16* __restrict__ ol,
                   float* __restrict__ part) {
  __shared__ __align__(16) u16 sm[12288];   // 24 KB
  __shared__ float ls[2][64];

  const int idx  = xcd_swz(blockIdx.x, gridDim.x);
  const int tid  = threadIdx.x;
  const int w    = tid >> 6;           // 0..1
  const int lane = tid & 63;

  if (idx >= 768) {
    // ================= CLS partial (one 256-key chunk per wave) ============
    const int chunk = (idx - 768) * 2 + w;      // 0..383
    const int p = chunk & (kClsSplit - 1);
    const int h = (chunk >> 4) % kH;
    const int b = chunk / (kClsSplit * kH);
    const int hOff = h * 256;
    const int keysPer = kS / kClsSplit;         // 256
    float* obuf = (float*)sm + w * 2112;        // [64][33] per wave (8.4 KB)

    float q[64];
    {
      const char* qp = qkvB + (size_t)(b * kS) * kRowB + hOff;
#pragma unroll
      for (int g = 0; g < 8; ++g) {
        const u16x8v hv = *(const u16x8v*)(qp + (g << 4));
        const u16x8v lv = *(const u16x8v*)(qp + 128 + (g << 4));
#pragma unroll
        for (int j = 0; j < 8; ++j) q[g * 8 + j] = bf2f(hv[j]) + bf2f(lv[j]);
      }
    }

    float oacc[64] = {};
    float l = 0.f;
    for (int i = 0; i < keysPer / 64; ++i) {
      const int sk = p * keysPer + i * 64 + lane;
      const char* rp = qkvB + (size_t)(b * kS + sk) * kRowB;
      const int swz = sk & 7;
      float dp = 0.f;
#pragma unroll
      for (int g = 0; g < 8; ++g) {
        const char* kp = rp + 3072 + hOff + ((g ^ swz) << 4);
        const u16x8v kh = *(const u16x8v*)kp;
        const u16x8v kl = *(const u16x8v*)(kp + 128);
#pragma unroll
        for (int j = 0; j < 8; ++j)
          dp = fmaf(q[g * 8 + j], bf2f(kh[j]) + bf2f(kl[j]), dp);
      }
      const float e = __expf(dp * kScale);
      l += e;
      const char* vp = rp + 6144 + hOff;
#pragma unroll
      for (int g = 0; g < 8; ++g) {
        const u16x8v vv = *(const u16x8v*)(vp + (g << 4));
#pragma unroll
        for (int j = 0; j < 8; ++j)
          oacc[g * 8 + j] = fmaf(e, bf2f(vv[j]), oacc[g * 8 + j]);
      }
    }

    float L = l;
#pragma unroll
    for (int off = 32; off > 0; off >>= 1) L += __shfl_xor(L, off);

    // two-pass cross-lane transpose-sum in 8.4 KB (wave-local; explicit fences)
    float sum = 0.f;
#pragma unroll
    for (int pass = 0; pass < 2; ++pass) {
#pragma unroll
      for (int d = 0; d < 32; ++d) obuf[lane * 33 + d] = oacc[pass * 32 + d];
      asm volatile("s_waitcnt lgkmcnt(0)" ::: "memory");
      __builtin_amdgcn_sched_barrier(0);
      if ((lane >> 5) == pass) {
        const int cc = lane & 31;
        for (int ln = 0; ln < 64; ++ln) sum += obuf[ln * 33 + cc];
      }
      asm volatile("s_waitcnt lgkmcnt(0)" ::: "memory");
      __builtin_amdgcn_sched_barrier(0);
    }

    float* dst = part + (size_t)chunk * 66;
    dst[lane] = sum;
    if (lane == 0) dst[64] = L;
    return;
  }

  // ================= windowed attention (round-16 config) =================
  u16* KsH = sm;
  u16* KsL = sm + 4096;
  u16* VsT = sm + 8192;

  const int half = idx & 1;
  const int c = (idx >> 1) % kC;
  const int h = ((idx >> 1) / kC) % kH;
  const int b = idx / (2 * kC * kH);
  const int l31  = lane & 31;
  const int h5   = lane >> 5;
  const int hOff = h * 256;
  const int qbase = c * kChunk + half * 128 + w * 64;

  bf16x8 Qh[2][4], Ql[2][4];
#pragma unroll
  for (int ti = 0; ti < 2; ++ti) {
    const size_t grow = (size_t)(b * kS + qbase + ti * 32 + l31);
#pragma unroll
    for (int ksl = 0; ksl < 4; ++ksl) {
      const char* p = qkvB + grow * kRowB + hOff + ((ksl * 2 + h5) << 4);
      Qh[ti][ksl] = *(const bf16x8*)p;
      Ql[ti][ksl] = *(const bf16x8*)(p + 128);
    }
  }

  f32x16 Oacc[2][2];
#pragma unroll
  for (int a = 0; a < 2; ++a)
#pragma unroll
    for (int d = 0; d < 2; ++d)
#pragma unroll
      for (int i = 0; i < 16; ++i) Oacc[a][d][i] = 0.f;
  float lsA[2] = {0.f, 0.f};

  const int clo = (c > 0) ? c - 1 : 0;
  const int chi = (c < kC - 1) ? c + 1 : kC - 1;
  const int nwin = (chi - clo + 1) * 4;
  const int ntiles = nwin + ((clo != 0) ? 1 : 0);

  U32x4 pa[2][4];

  for (int tt = 0; tt < ntiles; ++tt) {
    const bool isCls = (tt >= nwin);
    const int srow = isCls ? 0 : (clo * kChunk + tt * 64);

    __syncthreads();
#pragma unroll
    for (int j = 0; j < 4; ++j) {
      const int cb = w * 256 + j * 64;     // wave-uniform LDS chunk base
      const int ch = cb + lane;
      const size_t gr = (size_t)(b * kS + srow + (ch >> 3)) * kRowB + ((ch & 7) << 4);
      glds16(qkvB + gr + 3072 + hOff,       &KsH[cb * 8]);
      glds16(qkvB + gr + 3072 + hOff + 128, &KsL[cb * 8]);
      glds16(qkvB + gr + 6144 + hOff + 128, &VsT[cb * 8]);
    }
    __syncthreads();

#pragma unroll
    for (int kt = 0; kt < 2; ++kt) {
      bf16x8 KH[4], KL[4];
      const int krow = kt * 32 + l31;
#pragma unroll
      for (int ksl = 0; ksl < 4; ++ksl) {
        const int gg = (((ksl * 2 + h5) ^ (krow & 7)) << 3);
        KH[ksl] = *(const bf16x8*)&KsH[krow * 64 + gg];
        KL[ksl] = *(const bf16x8*)&KsL[krow * 64 + gg];
      }
#pragma unroll
      for (int ti = 0; ti < 2; ++ti) {
        f32x16 S;
#pragma unroll
        for (int i = 0; i < 16; ++i) S[i] = 0.f;
        __builtin_amdgcn_s_setprio(1);
#pragma unroll
        for (int ksl = 0; ksl < 4; ++ksl) {
          S = __builtin_amdgcn_mfma_f32_32x32x16_bf16(KH[ksl], Qh[ti][ksl], S, 0, 0, 0);
          S = __builtin_amdgcn_mfma_f32_32x32x16_bf16(KH[ksl], Ql[ti][ksl], S, 0, 0, 0);
          S = __builtin_amdgcn_mfma_f32_32x32x16_bf16(KL[ksl], Qh[ti][ksl], S, 0, 0, 0);
        }
        __builtin_amdgcn_s_setprio(0);
        unsigned int wpk[4][2], sw[4][2];
        float lacc = 0.f;
#pragma unroll
        for (int m = 0; m < 4; ++m) {
          float e[4];
#pragma unroll
          for (int r = 0; r < 4; ++r) {
            float ev = __expf(S[4 * m + r] * kScale);
            if (isCls && !(kt == 0 && m == 0 && r == 0 && h5 == 0)) ev = 0.f;
            e[r] = ev;
          }
          lacc += (e[0] + e[1]) + (e[2] + e[3]);
          wpk[m][0] = pkbf(e[0], e[1]);
          wpk[m][1] = pkbf(e[2], e[3]);
        }
        lsA[ti] += lacc;
#pragma unroll
        for (int m = 0; m < 4; ++m) {
          sw[m][0] = __shfl_xor(wpk[m][0], 32);
          sw[m][1] = __shfl_xor(wpk[m][1], 32);
        }
#pragma unroll
        for (int jj = 0; jj < 2; ++jj) {
          const int m0 = 2 * jj, m1 = 2 * jj + 1;
          U32x4& P = pa[ti][kt * 2 + jj];
          P.u[0] = h5 ? sw[m1][0]  : wpk[m0][0];
          P.u[1] = h5 ? sw[m1][1]  : wpk[m0][1];
          P.u[2] = h5 ? wpk[m1][0] : sw[m0][0];
          P.u[3] = h5 ? wpk[m1][1] : sw[m0][1];
        }
      }
    }

    __builtin_amdgcn_s_setprio(1);
#pragma unroll
    for (int sl = 0; sl < 4; ++sl) {
#pragma unroll
      for (int dt = 0; dt < 2; ++dt) {
        const int vrow = dt * 32 + l31;
        const bf16x8 vb =
            *(const bf16x8*)&VsT[vrow * 64 + ((((sl * 2 + h5) ^ (vrow & 7))) << 3)];
        Oacc[0][dt] = __builtin_amdgcn_mfma_f32_32x32x16_bf16(pa[0][sl].v, vb, Oacc[0][dt], 0, 0, 0);
        Oacc[1][dt] = __builtin_amdgcn_mfma_f32_32x32x16_bf16(pa[1][sl].v, vb, Oacc[1][dt], 0, 0, 0);
      }
    }
    __builtin_amdgcn_s_setprio(0);
  }

#pragma unroll
  for (int ti = 0; ti < 2; ++ti) {
    float v = lsA[ti];
    v += __shfl_xor(v, 32);
    ls[w][ti * 32 + l31] = v;
  }

#pragma unroll
  for (int ti = 0; ti < 2; ++ti)
#pragma unroll
    for (int m = 0; m < 4; ++m)
#pragma unroll
      for (int r = 0; r < 4; ++r) {
        const int qr = r + 8 * m + 4 * h5;
        const float inv = 1.0f / ls[w][ti * 32 + qr];
        const size_t grow = (size_t)(b * kS + qbase + ti * 32 + qr);
#pragma unroll
        for (int dt = 0; dt < 2; ++dt) {
          const float val = Oacc[ti][dt][4 * m + r] * inv;
          const u16 hb = f2bf(val);
          const size_t o = grow * (size_t)kE + h * 64 + dt * 32 + l31;
          oh[o] = hb;
          ol[o] = f2bf(val - bf2f(hb));
        }
      }
}

}  // namespace

// ---------------------------------------------------------------------------
extern "C" void kernel_launch(void* const* d_in, const int* in_sizes, int n_in,
                              void* d_out, int out_size, void* d_ws, size_t ws_size,
                              hipStream_t stream) {
  const float* x      = (const float*)d_in[0];
  const int*   coords = (const int*)d_in[1];
  const float* Wqkv   = (const float*)d_in[2];
  const float* bqkv   = (const float*)d_in[3];
  const float* Wout   = (const float*)d_in[4];
  const float* bout   = (const float*)d_in[5];
  float* out = (float*)d_out;

  // Workspace (100,663,296 B):
  //   A [0 .. 75,497,472)  packed qkv [B*S][9216B] written by fused QKV GEMM
  //       epilogue (aliased post-attention: WoTh @0)
  //   B [75,497,472 .. +25,165,824)  phase1: WqTh @0; phase2: oh @0,
  //       ol @+12,582,912
  // d_out: cls partials scratch (dead until final GEMM overwrites it).
  char* wsb = (char*)d_ws;
  char*  qkvB = wsb;
  u16* WoTh = (u16*)wsb;
  char* rb = wsb + 75497472;
  u16* WqTh = (u16*)rb;
  u16* oh   = (u16*)rb;
  u16* ol   = (u16*)(rb + 12582912);
  float* clsPart = out;

  const int M = kB * kS;  // 8192

  // 1. Transpose+bf16 W_qkv (hi only)
  wsplit_q<<<432, 256, 0, stream>>>(Wqkv, WqTh);

  // 2. QKV projection: x fp32 read directly, in-kernel hi/lo split,
  //    fused rope/pack/V^T epilogue -> packed qkvB  (no x pre-split pass)
  {
    const int nwg = (kQKV / 128) * (M / 128);   // 1152, %8==0
    gemm_qkv<<<nwg, 256, 0, stream>>>(x, WqTh, bqkv, qkvB, coords, M, kQKV, kE);
  }

  // 3. Windowed attention + fused CLS partials (960 blocks) -> oh/ol, clsPart
  attn_win_mfma<<<960, 128, 0, stream>>>(qkvB, oh, ol, clsPart);

  // 4. tail: transpose+bf16 W_out (dead qkv space) + CLS combine
  wsplit_comb<<<168, 256, 0, stream>>>(Wout, WoTh, clsPart, oh, ol);

  // 5. Output projection (thin 64x128 tiles, 768 blocks)
  {
    const int nwg = (kE / 128) * (M / 64);      // 768, %8==0
    gemm_thin<<<nwg, 256, 0, stream>>>(oh, ol, WoTh, bout, out, M, kE, kE);
  }
}

// Round 20
// 187.070 us; speedup vs baseline: 1.0434x; 1.0434x over previous
//
#include <hip/hip_runtime.h>

namespace {

typedef unsigned short u16;
typedef __bf16 bf16x8 __attribute__((ext_vector_type(8)));
typedef __bf16 bf16x2 __attribute__((ext_vector_type(2)));
typedef float f32x4 __attribute__((ext_vector_type(4)));
typedef float f32x16 __attribute__((ext_vector_type(16)));
typedef u16 u16x8v __attribute__((ext_vector_type(8)));
struct alignas(8) u16x4 { u16 x, y, z, w; };
union U32x4 { unsigned int u[4]; bf16x8 v; };

constexpr int kS    = 4096;
constexpr int kE    = 768;
constexpr int kH    = 12;
constexpr int kD    = 64;
constexpr int kQKV  = 2304;   // 3*E
constexpr int kChunk = 256;
constexpr int kC    = 16;     // S / CHUNK
constexpr int kB    = 2;
constexpr float kScale = 0.125f;  // 1/sqrt(64)
constexpr int kRowB = 9216;       // qkv row bytes
constexpr int kClsSplit = 16;     // key-chunks per (b,h) for CLS attention
constexpr float kL2 = 0.83048202372184058696f;  // log2(10000)/16

// ---- bf16 helpers (RNE) ---------------------------------------------------
__device__ __forceinline__ u16 f2bf(float f) {
  unsigned int u = __float_as_uint(f);
  u += 0x7FFFu + ((u >> 16) & 1u);
  return (u16)(u >> 16);
}
__device__ __forceinline__ float bf2f(u16 h) {
  return __uint_as_float(((unsigned int)h) << 16);
}
// packed pair via casts -> v_cvt_pk_bf16_f32 (RNE, same bits as f2bf here)
__device__ __forceinline__ unsigned int pkbf(float a, float b) {
  bf16x2 p;
  p[0] = (__bf16)a;
  p[1] = (__bf16)b;
  return __builtin_bit_cast(unsigned int, p);
}

// ---- XCD-aware bijective block swizzle (grid % 8 == 0) ---------------------
__device__ __forceinline__ int xcd_swz(int bid, int nwg) {
  const int cpx = nwg >> 3;
  return (bid & 7) * cpx + (bid >> 3);
}

// ---- async global->LDS, 16B per lane --------------------------------------
__device__ __forceinline__ void glds16(const void* g, void* l) {
  __builtin_amdgcn_global_load_lds(
      (const __attribute__((address_space(1))) unsigned int*)g,
      (__attribute__((address_space(3))) unsigned int*)l, 16, 0, 0);
}

// ---------------------------------------------------------------------------
// wsplit body: W[K][N] fp32 -> Th[N][K] bf16 (transposed, hi only).
// ---------------------------------------------------------------------------
__device__ __forceinline__ void wsplit_body(const float* __restrict__ W,
                                            u16* __restrict__ Th, int K, int N,
                                            int bid, int t, float (*tile)[65]) {
  const int ntiles = N >> 6;
  const int n0 = (bid % ntiles) << 6;
  const int k0 = (bid / ntiles) << 6;
  const int r  = t >> 2;
  const int cs = (t & 3) << 4;
  const float* src = W + (size_t)(k0 + r) * N + n0 + cs;
#pragma unroll
  for (int i = 0; i < 4; ++i) {
    float4 v = *(const float4*)(src + 4 * i);
    tile[r][cs + 4 * i + 0] = v.x;
    tile[r][cs + 4 * i + 1] = v.y;
    tile[r][cs + 4 * i + 2] = v.z;
    tile[r][cs + 4 * i + 3] = v.w;
  }
  __syncthreads();
  u16* dh = Th + (size_t)(n0 + r) * K + k0 + cs;
#pragma unroll
  for (int i = 0; i < 4; ++i) {
    u16x4 hq;
    hq.x = f2bf(tile[cs + 4 * i + 0][r]);
    hq.y = f2bf(tile[cs + 4 * i + 1][r]);
    hq.z = f2bf(tile[cs + 4 * i + 2][r]);
    hq.w = f2bf(tile[cs + 4 * i + 3][r]);
    *(u16x4*)(dh + 4 * i) = hq;
  }
}

// ---------------------------------------------------------------------------
// prep: blocks [0,3072) = x pre-split; blocks [3072,3504) = wsplit(W_qkv).
// ---------------------------------------------------------------------------
__global__ __launch_bounds__(256)
void prep(const float* __restrict__ x, u16* __restrict__ xh, u16* __restrict__ xl,
          const float* __restrict__ Wq, u16* __restrict__ WqTh) {
  __shared__ float tile[64][65];
  if (blockIdx.x < 3072) {
    const size_t i8 = ((size_t)blockIdx.x * 256 + threadIdx.x) * 8;
    const float4 v0 = *(const float4*)(x + i8);
    const float4 v1 = *(const float4*)(x + i8 + 4);
    const float f[8] = {v0.x, v0.y, v0.z, v0.w, v1.x, v1.y, v1.z, v1.w};
    u16x8v hv, lv;
#pragma unroll
    for (int j = 0; j < 8; ++j) {
      const u16 hb = f2bf(f[j]);
      hv[j] = hb;
      lv[j] = f2bf(f[j] - bf2f(hb));
    }
    *(u16x8v*)(xh + i8) = hv;
    *(u16x8v*)(xl + i8) = lv;
  } else {
    wsplit_body(Wq, WqTh, kE, kQKV, blockIdx.x - 3072, threadIdx.x, tile);
  }
}

// ---------------------------------------------------------------------------
// tail: blocks [0,144) = wsplit(W_out); blocks [144,168) = cls combine.
// ---------------------------------------------------------------------------
__global__ __launch_bounds__(256)
void wsplit_comb(const float* __restrict__ Wout, u16* __restrict__ WoTh,
                 const float* __restrict__ part,
                 u16* __restrict__ oh, u16* __restrict__ ol) {
  __shared__ float tile[64][65];
  if (blockIdx.x < 144) {
    wsplit_body(Wout, WoTh, kE, kE, blockIdx.x, threadIdx.x, tile);
  } else {
    if (threadIdx.x >= 64) return;
    const int bid = blockIdx.x - 144;      // 0..23
    const int h = bid % kH;
    const int b = bid / kH;
    const int lane = threadIdx.x;
    const float* src = part + (size_t)((b * kH + h) * kClsSplit) * 66;
    float s = 0.f, L = 0.f;
#pragma unroll
    for (int p = 0; p < kClsSplit; ++p) {
      s += src[p * 66 + lane];
      L += src[p * 66 + 64];
    }
    const float v = s / L;
    const u16 hb = f2bf(v);
    const size_t off0 = (size_t)(b * kS) * kE + h * kD + lane;
    oh[off0] = hb;
    ol[off0] = f2bf(v - bf2f(hb));
  }
}

// ---------------------------------------------------------------------------
// Split-bf16 MFMA GEMM (round-16 proven): 128x128 tile, 2-term, depth-2
// pipelined, LDS group-XOR swizzle, fused rope/pack/V^T epilogue (QKV=true).
// ---------------------------------------------------------------------------
template <bool QKV>
__global__ __launch_bounds__(256, 2)
void gemm_mfma(const u16* __restrict__ Ahg, const u16* __restrict__ Alg,
               const u16* __restrict__ Bhg,
               const float* __restrict__ bias, float* __restrict__ C,
               char* __restrict__ outPk, const int* __restrict__ coords,
               int M, int N, int K) {
  __shared__ __align__(16) u16 smem[24576];
  u16* AsH = smem;
  u16* AsL = smem + 8192;
  u16* BsH = smem + 16384;

  const int nwg = gridDim.x;
  const int lid = xcd_swz(blockIdx.x, nwg);
  const int nTiles = N >> 7;
  const int m0 = (lid / nTiles) << 7;
  const int n0 = (lid % nTiles) << 7;

  const int tid  = threadIdx.x;
  const int wave = tid >> 6;
  const int lane = tid & 63;
  const int l15  = lane & 15;
  const int khf  = lane >> 4;
  const int wm   = wave >> 1;
  const int wn   = wave & 1;

  const int c0 = wave * 2, c1 = wave * 2 + 1;
  const int rr = lane >> 2;
  const int gg = lane & 3;
  const int gsw = gg ^ ((rr >> 1) & 3);          // pre-swizzled source group
  const int kg  = khf ^ ((l15 >> 1) & 3);        // swizzled read slot

  const size_t bOff0 = (size_t)(n0 + c0 * 16 + rr) * K + gsw * 8;
  const size_t bOff1 = (size_t)(n0 + c1 * 16 + rr) * K + gsw * 8;
  const size_t aOff0 = (size_t)(m0 + c0 * 16 + rr) * K + gsw * 8;
  const size_t aOff1 = (size_t)(m0 + c1 * 16 + rr) * K + gsw * 8;

  auto STAGE = [&](int p, int k0) {
    glds16(Bhg + bOff0 + k0, BsH + p * 4096 + (c0 * 16) * 32);
    glds16(Bhg + bOff1 + k0, BsH + p * 4096 + (c1 * 16) * 32);
    glds16(Ahg + aOff0 + k0, AsH + p * 4096 + (c0 * 16) * 32);
    glds16(Ahg + aOff1 + k0, AsH + p * 4096 + (c1 * 16) * 32);
    glds16(Alg + aOff0 + k0, AsL + p * 4096 + (c0 * 16) * 32);
    glds16(Alg + aOff1 + k0, AsL + p * 4096 + (c1 * 16) * 32);
  };

  f32x4 acc[4][4];
#pragma unroll
  for (int i = 0; i < 4; ++i)
#pragma unroll
    for (int j = 0; j < 4; ++j) acc[i][j] = (f32x4){0.f, 0.f, 0.f, 0.f};

  auto COMPUTE = [&](int p) {
    bf16x8 fah[4], fal[4], fbh[4];
#pragma unroll
    for (int f = 0; f < 4; ++f) {
      fah[f] = *(const bf16x8*)&AsH[p * 4096 + (wm * 64 + f * 16 + l15) * 32 + kg * 8];
      fal[f] = *(const bf16x8*)&AsL[p * 4096 + (wm * 64 + f * 16 + l15) * 32 + kg * 8];
      fbh[f] = *(const bf16x8*)&BsH[p * 4096 + (wn * 64 + f * 16 + l15) * 32 + kg * 8];
    }
#pragma unroll
    for (int mi = 0; mi < 4; ++mi)
#pragma unroll
      for (int ni = 0; ni < 4; ++ni)
        acc[mi][ni] = __builtin_amdgcn_mfma_f32_16x16x32_bf16(fah[mi], fbh[ni], acc[mi][ni], 0, 0, 0);
#pragma unroll
    for (int mi = 0; mi < 4; ++mi)
#pragma unroll
      for (int ni = 0; ni < 4; ++ni)
        acc[mi][ni] = __builtin_amdgcn_mfma_f32_16x16x32_bf16(fal[mi], fbh[ni], acc[mi][ni], 0, 0, 0);
  };

  STAGE(0, 0);
  STAGE(1, 32);
  int cur = 0;

  for (int k0 = 0; k0 < K - 32; k0 += 32) {
    asm volatile("s_waitcnt vmcnt(6)" ::: "memory");
    __builtin_amdgcn_sched_barrier(0);
    __builtin_amdgcn_s_barrier();

    COMPUTE(cur);

    __builtin_amdgcn_sched_barrier(0);
    asm volatile("s_waitcnt lgkmcnt(0)" ::: "memory");
    __builtin_amdgcn_s_barrier();
    if (k0 + 64 < K) STAGE(cur, k0 + 64);
    cur ^= 1;
  }

  asm volatile("s_waitcnt vmcnt(0)" ::: "memory");
  __builtin_amdgcn_sched_barrier(0);
  __builtin_amdgcn_s_barrier();
  COMPUTE(cur);

  if constexpr (!QKV) {
#pragma unroll
    for (int ni = 0; ni < 4; ++ni) {
      const int col = n0 + wn * 64 + ni * 16 + l15;
      const float bv = bias[col];
#pragma unroll
      for (int mi = 0; mi < 4; ++mi) {
        const int rbase = m0 + wm * 64 + mi * 16 + khf * 4;
#pragma unroll
        for (int r = 0; r < 4; ++r)
          C[(size_t)(rbase + r) * N + col] = acc[mi][ni][r] + bv;
      }
    }
  } else {
    __syncthreads();   // all LDS staging reads done; smem free for bounce

    const int col64  = (n0 >> 6) + wn;   // 0..35
    const int sector = col64 / 12;       // 0=q, 1=k, 2=v
    const int hh     = col64 % 12;
    const int rowbase = m0 + wm * 64;    // 64-aligned

    if (sector < 2) {
      const int sel = sector;
#pragma unroll
      for (int mi = 0; mi < 4; ++mi)
#pragma unroll
        for (int r = 0; r < 4; ++r) {
          const int row = rowbase + mi * 16 + khf * 4 + r;
          const int bb = row >> 12;
          const int ss = row & 4095;
          float cx = 0.f, cy = 0.f;
          if (ss >= 1) {
            const size_t ci = ((size_t)bb * (kS - 1) + (ss - 1)) * 2;
            cx = (float)coords[ci]     * (1.0f / 100000.0f);
            cy = (float)coords[ci + 1] * (1.0f / 100000.0f);
          }
          const int swz = (sel == 1) ? (ss & 7) : 0;
          char* base = outPk + (size_t)row * kRowB + sel * 3072 + hh * 256;
#pragma unroll
          for (int ni = 0; ni < 4; ++ni) {
            const int d = ni * 16 + l15;
            const float v0 = acc[mi][ni][r] + bias[n0 + wn * 64 + ni * 16 + l15];
            const float pv = __shfl_xor(v0, 1);   // partner d^1 (all lanes exec)
            float nv = v0;
            if (ss >= 1) {
              const float coord = (d < 32) ? cx : cy;
              const float ang = coord * exp2f(-(float)((d >> 1) & 15) * kL2);
              const float sn = __sinf(ang), cn = __cosf(ang);
              nv = (d & 1) ? fmaf(v0, cn, pv * sn) : fmaf(v0, cn, -pv * sn);
            }
            const u16 hb = f2bf(nv);
            const u16 lb = f2bf(nv - bf2f(hb));
            const int gofs = (((d >> 3) ^ swz) << 4) + (d & 7) * 2;
            *(u16*)(base + gofs) = hb;
            *(u16*)(base + 128 + gofs) = lb;
          }
        }
    } else {
      u16* ldsT = smem + wave * 4352;    // 64 x 68 u16 per wave (8.5 KB)
#pragma unroll
      for (int mi = 0; mi < 4; ++mi)
#pragma unroll
        for (int ni = 0; ni < 4; ++ni)
#pragma unroll
          for (int r = 0; r < 4; ++r) {
            const int key = mi * 16 + khf * 4 + r;   // row within 64-group
            const int row = rowbase + key;
            const int d = ni * 16 + l15;
            const float v0 = acc[mi][ni][r] + bias[n0 + wn * 64 + ni * 16 + l15];
            const u16 hb = f2bf(v0);
            *(u16*)(outPk + (size_t)row * kRowB + 6144 + hh * 256 + d * 2) = hb;
            ldsT[d * 68 + key] = hb;
          }
      const int dd = lane;               // V^T row = d
      char* vbase = outPk + (size_t)(rowbase + dd) * kRowB + 6144 + hh * 256 + 128;
#pragma unroll
      for (int kgx = 0; kgx < 8; ++kgx) {
        const u16x4 a0 = *(const u16x4*)&ldsT[dd * 68 + kgx * 8];
        const u16x4 a1 = *(const u16x4*)&ldsT[dd * 68 + kgx * 8 + 4];
        char* dst = vbase + ((kgx ^ (dd & 7)) << 4);
        *(u16x4*)dst = a0;
        *(u16x4*)(dst + 8) = a1;
      }
    }
  }
}

// ---------------------------------------------------------------------------
// Thin GEMM for out-projection (round-17 proven): 64x128 tile, depth-2
// pipelined, LDS group-XOR swizzle.
// ---------------------------------------------------------------------------
__global__ __launch_bounds__(256, 2)
void gemm_thin(const u16* __restrict__ Ahg, const u16* __restrict__ Alg,
               const u16* __restrict__ Bhg,
               const float* __restrict__ bias, float* __restrict__ C,
               int M, int N, int K) {
  __shared__ __align__(16) u16 smem[16384];   // 2 x (Ah 2048 | Al 2048 | B 4096)
  const int nwg = gridDim.x;
  const int lid = xcd_swz(blockIdx.x, nwg);
  const int nTiles = N >> 7;
  const int m0 = (lid / nTiles) << 6;
  const int n0 = (lid % nTiles) << 7;

  const int tid  = threadIdx.x;
  const int wave = tid >> 6;
  const int lane = tid & 63;
  const int l15  = lane & 15;
  const int khf  = lane >> 4;

  const int rr = lane >> 2;
  const int gg = lane & 3;
  const int gsw = gg ^ ((rr >> 1) & 3);
  const int kg  = khf ^ ((l15 >> 1) & 3);

  const size_t aOff  = (size_t)(m0 + wave * 16 + rr) * K + gsw * 8;
  const size_t bOff0 = (size_t)(n0 + (2 * wave) * 16 + rr) * K + gsw * 8;
  const size_t bOff1 = (size_t)(n0 + (2 * wave + 1) * 16 + rr) * K + gsw * 8;

  auto STAGE = [&](int p, int k0) {
    u16* base = smem + p * 8192;
    glds16(Ahg + aOff + k0,  base + (wave * 16) * 32);
    glds16(Alg + aOff + k0,  base + 2048 + (wave * 16) * 32);
    glds16(Bhg + bOff0 + k0, base + 4096 + (2 * wave * 16) * 32);
    glds16(Bhg + bOff1 + k0, base + 4096 + ((2 * wave + 1) * 16) * 32);
  };

  f32x4 acc[4][2];
#pragma unroll
  for (int i = 0; i < 4; ++i)
#pragma unroll
    for (int j = 0; j < 2; ++j) acc[i][j] = (f32x4){0.f, 0.f, 0.f, 0.f};

  auto COMPUTE = [&](int p) {
    u16* base = smem + p * 8192;
    bf16x8 fah[4], fal[4], fbh[2];
#pragma unroll
    for (int f = 0; f < 4; ++f) {
      fah[f] = *(const bf16x8*)&base[(f * 16 + l15) * 32 + kg * 8];
      fal[f] = *(const bf16x8*)&base[2048 + (f * 16 + l15) * 32 + kg * 8];
    }
#pragma unroll
    for (int f = 0; f < 2; ++f)
      fbh[f] = *(const bf16x8*)&base[4096 + (wave * 32 + f * 16 + l15) * 32 + kg * 8];
#pragma unroll
    for (int mi = 0; mi < 4; ++mi)
#pragma unroll
      for (int ni = 0; ni < 2; ++ni)
        acc[mi][ni] = __builtin_amdgcn_mfma_f32_16x16x32_bf16(fah[mi], fbh[ni], acc[mi][ni], 0, 0, 0);
#pragma unroll
    for (int mi = 0; mi < 4; ++mi)
#pragma unroll
      for (int ni = 0; ni < 2; ++ni)
        acc[mi][ni] = __builtin_amdgcn_mfma_f32_16x16x32_bf16(fal[mi], fbh[ni], acc[mi][ni], 0, 0, 0);
  };

  STAGE(0, 0);
  STAGE(1, 32);
  int cur = 0;

  for (int k0 = 0; k0 < K - 32; k0 += 32) {
    asm volatile("s_waitcnt vmcnt(4)" ::: "memory");
    __builtin_amdgcn_sched_barrier(0);
    __builtin_amdgcn_s_barrier();

    COMPUTE(cur);

    __builtin_amdgcn_sched_barrier(0);
    asm volatile("s_waitcnt lgkmcnt(0)" ::: "memory");
    __builtin_amdgcn_s_barrier();
    if (k0 + 64 < K) STAGE(cur, k0 + 64);
    cur ^= 1;
  }

  asm volatile("s_waitcnt vmcnt(0)" ::: "memory");
  __builtin_amdgcn_sched_barrier(0);
  __builtin_amdgcn_s_barrier();
  COMPUTE(cur);

#pragma unroll
  for (int ni = 0; ni < 2; ++ni) {
    const int col = n0 + wave * 32 + ni * 16 + l15;
    const float bv = bias[col];
#pragma unroll
    for (int mi = 0; mi < 4; ++mi) {
      const int rbase = m0 + mi * 16 + khf * 4;
#pragma unroll
      for (int r = 0; r < 4; ++r)
        C[(size_t)(rbase + r) * N + col] = acc[mi][ni][r] + bv;
    }
  }
}

// ---------------------------------------------------------------------------
// Windowed attention + fused CLS partials. Grid = 768 attn + 192 cls = 960.
// LDS 24.5KB (cls obuf = two-pass [64][33] per wave) -> 6 blocks/CU.
// ---------------------------------------------------------------------------
__global__ __launch_bounds__(128)
void attn_win_mfma(const char* __restrict__ qkvB,
                   u16* __restrict__ oh, u16* __restrict__ ol,
                   float* __restrict__ part) {
  __shared__ __align__(16) u16 sm[12288];   // 24 KB
  __shared__ float ls[2][64];

  const int idx  = xcd_swz(blockIdx.x, gridDim.x);
  const int tid  = threadIdx.x;
  const int w    = tid >> 6;           // 0..1
  const int lane = tid & 63;

  if (idx >= 768) {
    // ================= CLS partial (one 256-key chunk per wave) ============
    const int chunk = (idx - 768) * 2 + w;      // 0..383
    const int p = chunk & (kClsSplit - 1);
    const int h = (chunk >> 4) % kH;
    const int b = chunk / (kClsSplit * kH);
    const int hOff = h * 256;
    const int keysPer = kS / kClsSplit;         // 256
    float* obuf = (float*)sm + w * 2112;        // [64][33] per wave (8.4 KB)

    float q[64];
    {
      const char* qp = qkvB + (size_t)(b * kS) * kRowB + hOff;
#pragma unroll
      for (int g = 0; g < 8; ++g) {
        const u16x8v hv = *(const u16x8v*)(qp + (g << 4));
        const u16x8v lv = *(const u16x8v*)(qp + 128 + (g << 4));
#pragma unroll
        for (int j = 0; j < 8; ++j) q[g * 8 + j] = bf2f(hv[j]) + bf2f(lv[j]);
      }
    }

    float oacc[64] = {};
    float l = 0.f;
    for (int i = 0; i < keysPer / 64; ++i) {
      const int sk = p * keysPer + i * 64 + lane;
      const char* rp = qkvB + (size_t)(b * kS + sk) * kRowB;
      const int swz = sk & 7;
      float dp = 0.f;
#pragma unroll
      for (int g = 0; g < 8; ++g) {
        const char* kp = rp + 3072 + hOff + ((g ^ swz) << 4);
        const u16x8v kh = *(const u16x8v*)kp;
        const u16x8v kl = *(const u16x8v*)(kp + 128);
#pragma unroll
        for (int j = 0; j < 8; ++j)
          dp = fmaf(q[g * 8 + j], bf2f(kh[j]) + bf2f(kl[j]), dp);
      }
      const float e = __expf(dp * kScale);
      l += e;
      const char* vp = rp + 6144 + hOff;
#pragma unroll
      for (int g = 0; g < 8; ++g) {
        const u16x8v vv = *(const u16x8v*)(vp + (g << 4));
#pragma unroll
        for (int j = 0; j < 8; ++j)
          oacc[g * 8 + j] = fmaf(e, bf2f(vv[j]), oacc[g * 8 + j]);
      }
    }

    float L = l;
#pragma unroll
    for (int off = 32; off > 0; off >>= 1) L += __shfl_xor(L, off);

    // two-pass cross-lane transpose-sum in 8.4 KB (wave-local; explicit fences)
    float sum = 0.f;
#pragma unroll
    for (int pass = 0; pass < 2; ++pass) {
#pragma unroll
      for (int d = 0; d < 32; ++d) obuf[lane * 33 + d] = oacc[pass * 32 + d];
      asm volatile("s_waitcnt lgkmcnt(0)" ::: "memory");
      __builtin_amdgcn_sched_barrier(0);
      if ((lane >> 5) == pass) {
        const int cc = lane & 31;
        for (int ln = 0; ln < 64; ++ln) sum += obuf[ln * 33 + cc];
      }
      asm volatile("s_waitcnt lgkmcnt(0)" ::: "memory");
      __builtin_amdgcn_sched_barrier(0);
    }

    float* dst = part + (size_t)chunk * 66;
    dst[lane] = sum;
    if (lane == 0) dst[64] = L;
    return;
  }

  // ================= windowed attention (round-16 config) =================
  u16* KsH = sm;
  u16* KsL = sm + 4096;
  u16* VsT = sm + 8192;

  const int half = idx & 1;
  const int c = (idx >> 1) % kC;
  const int h = ((idx >> 1) / kC) % kH;
  const int b = idx / (2 * kC * kH);
  const int l31  = lane & 31;
  const int h5   = lane >> 5;
  const int hOff = h * 256;
  const int qbase = c * kChunk + half * 128 + w * 64;

  bf16x8 Qh[2][4], Ql[2][4];
#pragma unroll
  for (int ti = 0; ti < 2; ++ti) {
    const size_t grow = (size_t)(b * kS + qbase + ti * 32 + l31);
#pragma unroll
    for (int ksl = 0; ksl < 4; ++ksl) {
      const char* p = qkvB + grow * kRowB + hOff + ((ksl * 2 + h5) << 4);
      Qh[ti][ksl] = *(const bf16x8*)p;
      Ql[ti][ksl] = *(const bf16x8*)(p + 128);
    }
  }

  f32x16 Oacc[2][2];
#pragma unroll
  for (int a = 0; a < 2; ++a)
#pragma unroll
    for (int d = 0; d < 2; ++d)
#pragma unroll
      for (int i = 0; i < 16; ++i) Oacc[a][d][i] = 0.f;
  float lsA[2] = {0.f, 0.f};

  const int clo = (c > 0) ? c - 1 : 0;
  const int chi = (c < kC - 1) ? c + 1 : kC - 1;
  const int nwin = (chi - clo + 1) * 4;
  const int ntiles = nwin + ((clo != 0) ? 1 : 0);

  U32x4 pa[2][4];

  for (int tt = 0; tt < ntiles; ++tt) {
    const bool isCls = (tt >= nwin);
    const int srow = isCls ? 0 : (clo * kChunk + tt * 64);

    __syncthreads();
#pragma unroll
    for (int j = 0; j < 4; ++j) {
      const int cb = w * 256 + j * 64;     // wave-uniform LDS chunk base
      const int ch = cb + lane;
      const size_t gr = (size_t)(b * kS + srow + (ch >> 3)) * kRowB + ((ch & 7) << 4);
      glds16(qkvB + gr + 3072 + hOff,       &KsH[cb * 8]);
      glds16(qkvB + gr + 3072 + hOff + 128, &KsL[cb * 8]);
      glds16(qkvB + gr + 6144 + hOff + 128, &VsT[cb * 8]);
    }
    __syncthreads();

#pragma unroll
    for (int kt = 0; kt < 2; ++kt) {
      bf16x8 KH[4], KL[4];
      const int krow = kt * 32 + l31;
#pragma unroll
      for (int ksl = 0; ksl < 4; ++ksl) {
        const int gg = (((ksl * 2 + h5) ^ (krow & 7)) << 3);
        KH[ksl] = *(const bf16x8*)&KsH[krow * 64 + gg];
        KL[ksl] = *(const bf16x8*)&KsL[krow * 64 + gg];
      }
#pragma unroll
      for (int ti = 0; ti < 2; ++ti) {
        f32x16 S;
#pragma unroll
        for (int i = 0; i < 16; ++i) S[i] = 0.f;
        __builtin_amdgcn_s_setprio(1);
#pragma unroll
        for (int ksl = 0; ksl < 4; ++ksl) {
          S = __builtin_amdgcn_mfma_f32_32x32x16_bf16(KH[ksl], Qh[ti][ksl], S, 0, 0, 0);
          S = __builtin_amdgcn_mfma_f32_32x32x16_bf16(KH[ksl], Ql[ti][ksl], S, 0, 0, 0);
          S = __builtin_amdgcn_mfma_f32_32x32x16_bf16(KL[ksl], Qh[ti][ksl], S, 0, 0, 0);
        }
        __builtin_amdgcn_s_setprio(0);
        unsigned int wpk[4][2], sw[4][2];
        float lacc = 0.f;
#pragma unroll
        for (int m = 0; m < 4; ++m) {
          float e[4];
#pragma unroll
          for (int r = 0; r < 4; ++r) {
            float ev = __expf(S[4 * m + r] * kScale);
            if (isCls && !(kt == 0 && m == 0 && r == 0 && h5 == 0)) ev = 0.f;
            e[r] = ev;
          }
          lacc += (e[0] + e[1]) + (e[2] + e[3]);
          wpk[m][0] = pkbf(e[0], e[1]);
          wpk[m][1] = pkbf(e[2], e[3]);
        }
        lsA[ti] += lacc;
#pragma unroll
        for (int m = 0; m < 4; ++m) {
          sw[m][0] = __shfl_xor(wpk[m][0], 32);
          sw[m][1] = __shfl_xor(wpk[m][1], 32);
        }
#pragma unroll
        for (int jj = 0; jj < 2; ++jj) {
          const int m0 = 2 * jj, m1 = 2 * jj + 1;
          U32x4& P = pa[ti][kt * 2 + jj];
          P.u[0] = h5 ? sw[m1][0]  : wpk[m0][0];
          P.u[1] = h5 ? sw[m1][1]  : wpk[m0][1];
          P.u[2] = h5 ? wpk[m1][0] : sw[m0][0];
          P.u[3] = h5 ? wpk[m1][1] : sw[m0][1];
        }
      }
    }

    __builtin_amdgcn_s_setprio(1);
#pragma unroll
    for (int sl = 0; sl < 4; ++sl) {
#pragma unroll
      for (int dt = 0; dt < 2; ++dt) {
        const int vrow = dt * 32 + l31;
        const bf16x8 vb =
            *(const bf16x8*)&VsT[vrow * 64 + ((((sl * 2 + h5) ^ (vrow & 7))) << 3)];
        Oacc[0][dt] = __builtin_amdgcn_mfma_f32_32x32x16_bf16(pa[0][sl].v, vb, Oacc[0][dt], 0, 0, 0);
        Oacc[1][dt] = __builtin_amdgcn_mfma_f32_32x32x16_bf16(pa[1][sl].v, vb, Oacc[1][dt], 0, 0, 0);
      }
    }
    __builtin_amdgcn_s_setprio(0);
  }

#pragma unroll
  for (int ti = 0; ti < 2; ++ti) {
    float v = lsA[ti];
    v += __shfl_xor(v, 32);
    ls[w][ti * 32 + l31] = v;
  }

#pragma unroll
  for (int ti = 0; ti < 2; ++ti)
#pragma unroll
    for (int m = 0; m < 4; ++m)
#pragma unroll
      for (int r = 0; r < 4; ++r) {
        const int qr = r + 8 * m + 4 * h5;
        const float inv = 1.0f / ls[w][ti * 32 + qr];
        const size_t grow = (size_t)(b * kS + qbase + ti * 32 + qr);
#pragma unroll
        for (int dt = 0; dt < 2; ++dt) {
          const float val = Oacc[ti][dt][4 * m + r] * inv;
          const u16 hb = f2bf(val);
          const size_t o = grow * (size_t)kE + h * 64 + dt * 32 + l31;
          oh[o] = hb;
          ol[o] = f2bf(val - bf2f(hb));
        }
      }
}

}  // namespace

// ---------------------------------------------------------------------------
extern "C" void kernel_launch(void* const* d_in, const int* in_sizes, int n_in,
                              void* d_out, int out_size, void* d_ws, size_t ws_size,
                              hipStream_t stream) {
  const float* x      = (const float*)d_in[0];
  const int*   coords = (const int*)d_in[1];
  const float* Wqkv   = (const float*)d_in[2];
  const float* bqkv   = (const float*)d_in[3];
  const float* Wout   = (const float*)d_in[4];
  const float* bout   = (const float*)d_in[5];
  float* out = (float*)d_out;

  // Workspace (100,663,296 B):
  //   A [0 .. 75,497,472)  packed qkv [B*S][9216B] written by fused QKV GEMM
  //       epilogue (aliased post-attention: WoTh @0)
  //   B [75,497,472 .. +25,165,824)  phase1: WqTh @0; phase2: oh @0,
  //       ol @+12,582,912
  // d_out doubles as scratch (stream-ordered): xh/xl, then cls partials,
  // then the final output overwrites it.
  char* wsb = (char*)d_ws;
  char*  qkvB = wsb;
  u16* WoTh = (u16*)wsb;
  char* rb = wsb + 75497472;
  u16* WqTh = (u16*)rb;
  u16* oh   = (u16*)rb;
  u16* ol   = (u16*)(rb + 12582912);
  u16* xh   = (u16*)d_out;
  u16* xl   = (u16*)((char*)d_out + 12582912);
  float* clsPart = out;

  const int M = kB * kS;  // 8192

  // 1. prep: x pre-split (scratch in d_out) + transpose+bf16 W_qkv
  prep<<<3504, 256, 0, stream>>>(x, xh, xl, Wqkv, WqTh);

  // 2. QKV projection with fused rope/pack/V^T epilogue -> packed qkvB
  {
    const int nwg = (kQKV / 128) * (M / 128);   // 1152, %8==0
    gemm_mfma<true><<<nwg, 256, 0, stream>>>(xh, xl, WqTh, bqkv, nullptr,
                                             qkvB, coords, M, kQKV, kE);
  }

  // 3. Windowed attention + fused CLS partials (960 blocks) -> oh/ol, clsPart
  attn_win_mfma<<<960, 128, 0, stream>>>(qkvB, oh, ol, clsPart);

  // 4. tail: transpose+bf16 W_out (dead qkv space) + CLS combine
  wsplit_comb<<<168, 256, 0, stream>>>(Wout, WoTh, clsPart, oh, ol);

  // 5. Output projection (thin 64x128 tiles, 768 blocks)
  {
    const int nwg = (kE / 128) * (M / 64);      // 768, %8==0
    gemm_thin<<<nwg, 256, 0, stream>>>(oh, ol, WoTh, bout, out, M, kE, kE);
  }
}

// Round 21
// 177.511 us; speedup vs baseline: 1.0996x; 1.0539x over previous
//
#include <hip/hip_runtime.h>

namespace {

typedef unsigned short u16;
typedef __bf16 bf16x8 __attribute__((ext_vector_type(8)));
typedef __bf16 bf16x2 __attribute__((ext_vector_type(2)));
typedef float f32x4 __attribute__((ext_vector_type(4)));
typedef float f32x16 __attribute__((ext_vector_type(16)));
typedef u16 u16x8v __attribute__((ext_vector_type(8)));
struct alignas(8) u16x4 { u16 x, y, z, w; };
union U32x4 { unsigned int u[4]; bf16x8 v; };

constexpr int kS    = 4096;
constexpr int kE    = 768;
constexpr int kH    = 12;
constexpr int kD    = 64;
constexpr int kQKV  = 2304;   // 3*E
constexpr int kChunk = 256;
constexpr int kC    = 16;     // S / CHUNK
constexpr int kB    = 2;
constexpr float kScale = 0.125f;  // 1/sqrt(64)
constexpr int kRowB = 9216;       // qkv row bytes
constexpr int kClsSplit = 16;     // key-chunks per (b,h) for CLS attention
constexpr float kL2 = 0.83048202372184058696f;  // log2(10000)/16

// ---- bf16 helpers (RNE) ---------------------------------------------------
__device__ __forceinline__ u16 f2bf(float f) {
  unsigned int u = __float_as_uint(f);
  u += 0x7FFFu + ((u >> 16) & 1u);
  return (u16)(u >> 16);
}
__device__ __forceinline__ float bf2f(u16 h) {
  return __uint_as_float(((unsigned int)h) << 16);
}
// packed pair via casts -> v_cvt_pk_bf16_f32 (RNE, same bits as f2bf here)
__device__ __forceinline__ unsigned int pkbf(float a, float b) {
  bf16x2 p;
  p[0] = (__bf16)a;
  p[1] = (__bf16)b;
  return __builtin_bit_cast(unsigned int, p);
}

// ---- XCD-aware bijective block swizzle (grid % 8 == 0) ---------------------
__device__ __forceinline__ int xcd_swz(int bid, int nwg) {
  const int cpx = nwg >> 3;
  return (bid & 7) * cpx + (bid >> 3);
}

// ---- async global->LDS, 16B per lane --------------------------------------
__device__ __forceinline__ void glds16(const void* g, void* l) {
  __builtin_amdgcn_global_load_lds(
      (const __attribute__((address_space(1))) unsigned int*)g,
      (__attribute__((address_space(3))) unsigned int*)l, 16, 0, 0);
}

// ---------------------------------------------------------------------------
// wsplit body: W[K][N] fp32 -> Th[N][K] bf16 (transposed, hi only).
// ---------------------------------------------------------------------------
__device__ __forceinline__ void wsplit_body(const float* __restrict__ W,
                                            u16* __restrict__ Th, int K, int N,
                                            int bid, int t, float (*tile)[65]) {
  const int ntiles = N >> 6;
  const int n0 = (bid % ntiles) << 6;
  const int k0 = (bid / ntiles) << 6;
  const int r  = t >> 2;
  const int cs = (t & 3) << 4;
  const float* src = W + (size_t)(k0 + r) * N + n0 + cs;
#pragma unroll
  for (int i = 0; i < 4; ++i) {
    float4 v = *(const float4*)(src + 4 * i);
    tile[r][cs + 4 * i + 0] = v.x;
    tile[r][cs + 4 * i + 1] = v.y;
    tile[r][cs + 4 * i + 2] = v.z;
    tile[r][cs + 4 * i + 3] = v.w;
  }
  __syncthreads();
  u16* dh = Th + (size_t)(n0 + r) * K + k0 + cs;
#pragma unroll
  for (int i = 0; i < 4; ++i) {
    u16x4 hq;
    hq.x = f2bf(tile[cs + 4 * i + 0][r]);
    hq.y = f2bf(tile[cs + 4 * i + 1][r]);
    hq.z = f2bf(tile[cs + 4 * i + 2][r]);
    hq.w = f2bf(tile[cs + 4 * i + 3][r]);
    *(u16x4*)(dh + 4 * i) = hq;
  }
}

// ---------------------------------------------------------------------------
// prep: blocks [0,3072) = x pre-split; blocks [3072,3504) = wsplit(W_qkv).
// ---------------------------------------------------------------------------
__global__ __launch_bounds__(256)
void prep(const float* __restrict__ x, u16* __restrict__ xh, u16* __restrict__ xl,
          const float* __restrict__ Wq, u16* __restrict__ WqTh) {
  __shared__ float tile[64][65];
  if (blockIdx.x < 3072) {
    const size_t i8 = ((size_t)blockIdx.x * 256 + threadIdx.x) * 8;
    const float4 v0 = *(const float4*)(x + i8);
    const float4 v1 = *(const float4*)(x + i8 + 4);
    const float f[8] = {v0.x, v0.y, v0.z, v0.w, v1.x, v1.y, v1.z, v1.w};
    u16x8v hv, lv;
#pragma unroll
    for (int j = 0; j < 8; ++j) {
      const u16 hb = f2bf(f[j]);
      hv[j] = hb;
      lv[j] = f2bf(f[j] - bf2f(hb));
    }
    *(u16x8v*)(xh + i8) = hv;
    *(u16x8v*)(xl + i8) = lv;
  } else {
    wsplit_body(Wq, WqTh, kE, kQKV, blockIdx.x - 3072, threadIdx.x, tile);
  }
}

// ---------------------------------------------------------------------------
// tail: blocks [0,144) = wsplit(W_out); blocks [144,168) = cls combine.
// ---------------------------------------------------------------------------
__global__ __launch_bounds__(256)
void wsplit_comb(const float* __restrict__ Wout, u16* __restrict__ WoTh,
                 const float* __restrict__ part,
                 u16* __restrict__ oh, u16* __restrict__ ol) {
  __shared__ float tile[64][65];
  if (blockIdx.x < 144) {
    wsplit_body(Wout, WoTh, kE, kE, blockIdx.x, threadIdx.x, tile);
  } else {
    if (threadIdx.x >= 64) return;
    const int bid = blockIdx.x - 144;      // 0..23
    const int h = bid % kH;
    const int b = bid / kH;
    const int lane = threadIdx.x;
    const float* src = part + (size_t)((b * kH + h) * kClsSplit) * 66;
    float s = 0.f, L = 0.f;
#pragma unroll
    for (int p = 0; p < kClsSplit; ++p) {
      s += src[p * 66 + lane];
      L += src[p * 66 + 64];
    }
    const float v = s / L;
    const u16 hb = f2bf(v);
    const size_t off0 = (size_t)(b * kS) * kE + h * kD + lane;
    oh[off0] = hb;
    ol[off0] = f2bf(v - bf2f(hb));
  }
}

// ---------------------------------------------------------------------------
// Split-bf16 MFMA GEMM (round-16 proven): 128x128 tile, 2-term, depth-2
// pipelined, LDS group-XOR swizzle, fused rope/pack/V^T epilogue (QKV=true).
// ---------------------------------------------------------------------------
template <bool QKV>
__global__ __launch_bounds__(256, 2)
void gemm_mfma(const u16* __restrict__ Ahg, const u16* __restrict__ Alg,
               const u16* __restrict__ Bhg,
               const float* __restrict__ bias, float* __restrict__ C,
               char* __restrict__ outPk, const int* __restrict__ coords,
               int M, int N, int K) {
  __shared__ __align__(16) u16 smem[24576];
  u16* AsH = smem;
  u16* AsL = smem + 8192;
  u16* BsH = smem + 16384;

  const int nwg = gridDim.x;
  const int lid = xcd_swz(blockIdx.x, nwg);
  const int nTiles = N >> 7;
  const int m0 = (lid / nTiles) << 7;
  const int n0 = (lid % nTiles) << 7;

  const int tid  = threadIdx.x;
  const int wave = tid >> 6;
  const int lane = tid & 63;
  const int l15  = lane & 15;
  const int khf  = lane >> 4;
  const int wm   = wave >> 1;
  const int wn   = wave & 1;

  const int c0 = wave * 2, c1 = wave * 2 + 1;
  const int rr = lane >> 2;
  const int gg = lane & 3;
  const int gsw = gg ^ ((rr >> 1) & 3);          // pre-swizzled source group
  const int kg  = khf ^ ((l15 >> 1) & 3);        // swizzled read slot

  const size_t bOff0 = (size_t)(n0 + c0 * 16 + rr) * K + gsw * 8;
  const size_t bOff1 = (size_t)(n0 + c1 * 16 + rr) * K + gsw * 8;
  const size_t aOff0 = (size_t)(m0 + c0 * 16 + rr) * K + gsw * 8;
  const size_t aOff1 = (size_t)(m0 + c1 * 16 + rr) * K + gsw * 8;

  auto STAGE = [&](int p, int k0) {
    glds16(Bhg + bOff0 + k0, BsH + p * 4096 + (c0 * 16) * 32);
    glds16(Bhg + bOff1 + k0, BsH + p * 4096 + (c1 * 16) * 32);
    glds16(Ahg + aOff0 + k0, AsH + p * 4096 + (c0 * 16) * 32);
    glds16(Ahg + aOff1 + k0, AsH + p * 4096 + (c1 * 16) * 32);
    glds16(Alg + aOff0 + k0, AsL + p * 4096 + (c0 * 16) * 32);
    glds16(Alg + aOff1 + k0, AsL + p * 4096 + (c1 * 16) * 32);
  };

  f32x4 acc[4][4];
#pragma unroll
  for (int i = 0; i < 4; ++i)
#pragma unroll
    for (int j = 0; j < 4; ++j) acc[i][j] = (f32x4){0.f, 0.f, 0.f, 0.f};

  auto COMPUTE = [&](int p) {
    bf16x8 fah[4], fal[4], fbh[4];
#pragma unroll
    for (int f = 0; f < 4; ++f) {
      fah[f] = *(const bf16x8*)&AsH[p * 4096 + (wm * 64 + f * 16 + l15) * 32 + kg * 8];
      fal[f] = *(const bf16x8*)&AsL[p * 4096 + (wm * 64 + f * 16 + l15) * 32 + kg * 8];
      fbh[f] = *(const bf16x8*)&BsH[p * 4096 + (wn * 64 + f * 16 + l15) * 32 + kg * 8];
    }
#pragma unroll
    for (int mi = 0; mi < 4; ++mi)
#pragma unroll
      for (int ni = 0; ni < 4; ++ni)
        acc[mi][ni] = __builtin_amdgcn_mfma_f32_16x16x32_bf16(fah[mi], fbh[ni], acc[mi][ni], 0, 0, 0);
#pragma unroll
    for (int mi = 0; mi < 4; ++mi)
#pragma unroll
      for (int ni = 0; ni < 4; ++ni)
        acc[mi][ni] = __builtin_amdgcn_mfma_f32_16x16x32_bf16(fal[mi], fbh[ni], acc[mi][ni], 0, 0, 0);
  };

  STAGE(0, 0);
  STAGE(1, 32);
  int cur = 0;

  for (int k0 = 0; k0 < K - 32; k0 += 32) {
    asm volatile("s_waitcnt vmcnt(6)" ::: "memory");
    __builtin_amdgcn_sched_barrier(0);
    __builtin_amdgcn_s_barrier();

    COMPUTE(cur);

    __builtin_amdgcn_sched_barrier(0);
    asm volatile("s_waitcnt lgkmcnt(0)" ::: "memory");
    __builtin_amdgcn_s_barrier();
    if (k0 + 64 < K) STAGE(cur, k0 + 64);
    cur ^= 1;
  }

  asm volatile("s_waitcnt vmcnt(0)" ::: "memory");
  __builtin_amdgcn_sched_barrier(0);
  __builtin_amdgcn_s_barrier();
  COMPUTE(cur);

  if constexpr (!QKV) {
#pragma unroll
    for (int ni = 0; ni < 4; ++ni) {
      const int col = n0 + wn * 64 + ni * 16 + l15;
      const float bv = bias[col];
#pragma unroll
      for (int mi = 0; mi < 4; ++mi) {
        const int rbase = m0 + wm * 64 + mi * 16 + khf * 4;
#pragma unroll
        for (int r = 0; r < 4; ++r)
          C[(size_t)(rbase + r) * N + col] = acc[mi][ni][r] + bv;
      }
    }
  } else {
    __syncthreads();   // all LDS staging reads done; smem free for bounce

    const int col64  = (n0 >> 6) + wn;   // 0..35
    const int sector = col64 / 12;       // 0=q, 1=k, 2=v
    const int hh     = col64 % 12;
    const int rowbase = m0 + wm * 64;    // 64-aligned

    if (sector < 2) {
      const int sel = sector;
#pragma unroll
      for (int mi = 0; mi < 4; ++mi)
#pragma unroll
        for (int r = 0; r < 4; ++r) {
          const int row = rowbase + mi * 16 + khf * 4 + r;
          const int bb = row >> 12;
          const int ss = row & 4095;
          float cx = 0.f, cy = 0.f;
          if (ss >= 1) {
            const size_t ci = ((size_t)bb * (kS - 1) + (ss - 1)) * 2;
            cx = (float)coords[ci]     * (1.0f / 100000.0f);
            cy = (float)coords[ci + 1] * (1.0f / 100000.0f);
          }
          const int swz = (sel == 1) ? (ss & 7) : 0;
          char* base = outPk + (size_t)row * kRowB + sel * 3072 + hh * 256;
#pragma unroll
          for (int ni = 0; ni < 4; ++ni) {
            const int d = ni * 16 + l15;
            const float v0 = acc[mi][ni][r] + bias[n0 + wn * 64 + ni * 16 + l15];
            const float pv = __shfl_xor(v0, 1);   // partner d^1 (all lanes exec)
            float nv = v0;
            if (ss >= 1) {
              const float coord = (d < 32) ? cx : cy;
              const float ang = coord * exp2f(-(float)((d >> 1) & 15) * kL2);
              const float sn = __sinf(ang), cn = __cosf(ang);
              nv = (d & 1) ? fmaf(v0, cn, pv * sn) : fmaf(v0, cn, -pv * sn);
            }
            const u16 hb = f2bf(nv);
            const u16 lb = f2bf(nv - bf2f(hb));
            const int gofs = (((d >> 3) ^ swz) << 4) + (d & 7) * 2;
            *(u16*)(base + gofs) = hb;
            *(u16*)(base + 128 + gofs) = lb;
          }
        }
    } else {
      u16* ldsT = smem + wave * 4352;    // 64 x 68 u16 per wave (8.5 KB)
#pragma unroll
      for (int mi = 0; mi < 4; ++mi)
#pragma unroll
        for (int ni = 0; ni < 4; ++ni)
#pragma unroll
          for (int r = 0; r < 4; ++r) {
            const int key = mi * 16 + khf * 4 + r;   // row within 64-group
            const int row = rowbase + key;
            const int d = ni * 16 + l15;
            const float v0 = acc[mi][ni][r] + bias[n0 + wn * 64 + ni * 16 + l15];
            const u16 hb = f2bf(v0);
            *(u16*)(outPk + (size_t)row * kRowB + 6144 + hh * 256 + d * 2) = hb;
            ldsT[d * 68 + key] = hb;
          }
      const int dd = lane;               // V^T row = d
      char* vbase = outPk + (size_t)(rowbase + dd) * kRowB + 6144 + hh * 256 + 128;
#pragma unroll
      for (int kgx = 0; kgx < 8; ++kgx) {
        const u16x4 a0 = *(const u16x4*)&ldsT[dd * 68 + kgx * 8];
        const u16x4 a1 = *(const u16x4*)&ldsT[dd * 68 + kgx * 8 + 4];
        char* dst = vbase + ((kgx ^ (dd & 7)) << 4);
        *(u16x4*)dst = a0;
        *(u16x4*)(dst + 8) = a1;
      }
    }
  }
}

// ---------------------------------------------------------------------------
// Thin GEMM for out-projection (round-17 proven): 64x128 tile, depth-2
// pipelined, LDS group-XOR swizzle.
// ---------------------------------------------------------------------------
__global__ __launch_bounds__(256, 2)
void gemm_thin(const u16* __restrict__ Ahg, const u16* __restrict__ Alg,
               const u16* __restrict__ Bhg,
               const float* __restrict__ bias, float* __restrict__ C,
               int M, int N, int K) {
  __shared__ __align__(16) u16 smem[16384];   // 2 x (Ah 2048 | Al 2048 | B 4096)
  const int nwg = gridDim.x;
  const int lid = xcd_swz(blockIdx.x, nwg);
  const int nTiles = N >> 7;
  const int m0 = (lid / nTiles) << 6;
  const int n0 = (lid % nTiles) << 7;

  const int tid  = threadIdx.x;
  const int wave = tid >> 6;
  const int lane = tid & 63;
  const int l15  = lane & 15;
  const int khf  = lane >> 4;

  const int rr = lane >> 2;
  const int gg = lane & 3;
  const int gsw = gg ^ ((rr >> 1) & 3);
  const int kg  = khf ^ ((l15 >> 1) & 3);

  const size_t aOff  = (size_t)(m0 + wave * 16 + rr) * K + gsw * 8;
  const size_t bOff0 = (size_t)(n0 + (2 * wave) * 16 + rr) * K + gsw * 8;
  const size_t bOff1 = (size_t)(n0 + (2 * wave + 1) * 16 + rr) * K + gsw * 8;

  auto STAGE = [&](int p, int k0) {
    u16* base = smem + p * 8192;
    glds16(Ahg + aOff + k0,  base + (wave * 16) * 32);
    glds16(Alg + aOff + k0,  base + 2048 + (wave * 16) * 32);
    glds16(Bhg + bOff0 + k0, base + 4096 + (2 * wave * 16) * 32);
    glds16(Bhg + bOff1 + k0, base + 4096 + ((2 * wave + 1) * 16) * 32);
  };

  f32x4 acc[4][2];
#pragma unroll
  for (int i = 0; i < 4; ++i)
#pragma unroll
    for (int j = 0; j < 2; ++j) acc[i][j] = (f32x4){0.f, 0.f, 0.f, 0.f};

  auto COMPUTE = [&](int p) {
    u16* base = smem + p * 8192;
    bf16x8 fah[4], fal[4], fbh[2];
#pragma unroll
    for (int f = 0; f < 4; ++f) {
      fah[f] = *(const bf16x8*)&base[(f * 16 + l15) * 32 + kg * 8];
      fal[f] = *(const bf16x8*)&base[2048 + (f * 16 + l15) * 32 + kg * 8];
    }
#pragma unroll
    for (int f = 0; f < 2; ++f)
      fbh[f] = *(const bf16x8*)&base[4096 + (wave * 32 + f * 16 + l15) * 32 + kg * 8];
#pragma unroll
    for (int mi = 0; mi < 4; ++mi)
#pragma unroll
      for (int ni = 0; ni < 2; ++ni)
        acc[mi][ni] = __builtin_amdgcn_mfma_f32_16x16x32_bf16(fah[mi], fbh[ni], acc[mi][ni], 0, 0, 0);
#pragma unroll
    for (int mi = 0; mi < 4; ++mi)
#pragma unroll
      for (int ni = 0; ni < 2; ++ni)
        acc[mi][ni] = __builtin_amdgcn_mfma_f32_16x16x32_bf16(fal[mi], fbh[ni], acc[mi][ni], 0, 0, 0);
  };

  STAGE(0, 0);
  STAGE(1, 32);
  int cur = 0;

  for (int k0 = 0; k0 < K - 32; k0 += 32) {
    asm volatile("s_waitcnt vmcnt(4)" ::: "memory");
    __builtin_amdgcn_sched_barrier(0);
    __builtin_amdgcn_s_barrier();

    COMPUTE(cur);

    __builtin_amdgcn_sched_barrier(0);
    asm volatile("s_waitcnt lgkmcnt(0)" ::: "memory");
    __builtin_amdgcn_s_barrier();
    if (k0 + 64 < K) STAGE(cur, k0 + 64);
    cur ^= 1;
  }

  asm volatile("s_waitcnt vmcnt(0)" ::: "memory");
  __builtin_amdgcn_sched_barrier(0);
  __builtin_amdgcn_s_barrier();
  COMPUTE(cur);

#pragma unroll
  for (int ni = 0; ni < 2; ++ni) {
    const int col = n0 + wave * 32 + ni * 16 + l15;
    const float bv = bias[col];
#pragma unroll
    for (int mi = 0; mi < 4; ++mi) {
      const int rbase = m0 + mi * 16 + khf * 4;
#pragma unroll
      for (int r = 0; r < 4; ++r)
        C[(size_t)(rbase + r) * N + col] = acc[mi][ni][r] + bv;
    }
  }
}

// ---------------------------------------------------------------------------
// Windowed attention + fused CLS partials. Grid = 768 attn + 192 cls = 960.
// NEW (r21): QK^T 2-term (KhQh + KhQl; K-lo term dropped -- error ~1e-4 via
// softmax averaging). K-lo staging removed: 8 glds/wave/tile, LDS 16.9 KB
// -> ~8 blocks/CU.
// ---------------------------------------------------------------------------
__global__ __launch_bounds__(128)
void attn_win_mfma(const char* __restrict__ qkvB,
                   u16* __restrict__ oh, u16* __restrict__ ol,
                   float* __restrict__ part) {
  __shared__ __align__(16) u16 sm[8448];   // 16.9 KB (attn 16 KB / cls 16.9 KB)
  __shared__ float ls[2][64];

  const int idx  = xcd_swz(blockIdx.x, gridDim.x);
  const int tid  = threadIdx.x;
  const int w    = tid >> 6;           // 0..1
  const int lane = tid & 63;

  if (idx >= 768) {
    // ================= CLS partial (one 256-key chunk per wave) ============
    const int chunk = (idx - 768) * 2 + w;      // 0..383
    const int p = chunk & (kClsSplit - 1);
    const int h = (chunk >> 4) % kH;
    const int b = chunk / (kClsSplit * kH);
    const int hOff = h * 256;
    const int keysPer = kS / kClsSplit;         // 256
    float* obuf = (float*)sm + w * 2112;        // [64][33] per wave (8.4 KB)

    float q[64];
    {
      const char* qp = qkvB + (size_t)(b * kS) * kRowB + hOff;
#pragma unroll
      for (int g = 0; g < 8; ++g) {
        const u16x8v hv = *(const u16x8v*)(qp + (g << 4));
        const u16x8v lv = *(const u16x8v*)(qp + 128 + (g << 4));
#pragma unroll
        for (int j = 0; j < 8; ++j) q[g * 8 + j] = bf2f(hv[j]) + bf2f(lv[j]);
      }
    }

    float oacc[64] = {};
    float l = 0.f;
    for (int i = 0; i < keysPer / 64; ++i) {
      const int sk = p * keysPer + i * 64 + lane;
      const char* rp = qkvB + (size_t)(b * kS + sk) * kRowB;
      const int swz = sk & 7;
      float dp = 0.f;
#pragma unroll
      for (int g = 0; g < 8; ++g) {
        const char* kp = rp + 3072 + hOff + ((g ^ swz) << 4);
        const u16x8v kh = *(const u16x8v*)kp;
        const u16x8v kl = *(const u16x8v*)(kp + 128);
#pragma unroll
        for (int j = 0; j < 8; ++j)
          dp = fmaf(q[g * 8 + j], bf2f(kh[j]) + bf2f(kl[j]), dp);
      }
      const float e = __expf(dp * kScale);
      l += e;
      const char* vp = rp + 6144 + hOff;
#pragma unroll
      for (int g = 0; g < 8; ++g) {
        const u16x8v vv = *(const u16x8v*)(vp + (g << 4));
#pragma unroll
        for (int j = 0; j < 8; ++j)
          oacc[g * 8 + j] = fmaf(e, bf2f(vv[j]), oacc[g * 8 + j]);
      }
    }

    float L = l;
#pragma unroll
    for (int off = 32; off > 0; off >>= 1) L += __shfl_xor(L, off);

    // two-pass cross-lane transpose-sum in 8.4 KB (wave-local; explicit fences)
    float sum = 0.f;
#pragma unroll
    for (int pass = 0; pass < 2; ++pass) {
#pragma unroll
      for (int d = 0; d < 32; ++d) obuf[lane * 33 + d] = oacc[pass * 32 + d];
      asm volatile("s_waitcnt lgkmcnt(0)" ::: "memory");
      __builtin_amdgcn_sched_barrier(0);
      if ((lane >> 5) == pass) {
        const int cc = lane & 31;
        for (int ln = 0; ln < 64; ++ln) sum += obuf[ln * 33 + cc];
      }
      asm volatile("s_waitcnt lgkmcnt(0)" ::: "memory");
      __builtin_amdgcn_sched_barrier(0);
    }

    float* dst = part + (size_t)chunk * 66;
    dst[lane] = sum;
    if (lane == 0) dst[64] = L;
    return;
  }

  // ================= windowed attention (2-term QK^T) ======================
  u16* KsH = sm;
  u16* VsT = sm + 4096;

  const int half = idx & 1;
  const int c = (idx >> 1) % kC;
  const int h = ((idx >> 1) / kC) % kH;
  const int b = idx / (2 * kC * kH);
  const int l31  = lane & 31;
  const int h5   = lane >> 5;
  const int hOff = h * 256;
  const int qbase = c * kChunk + half * 128 + w * 64;

  bf16x8 Qh[2][4], Ql[2][4];
#pragma unroll
  for (int ti = 0; ti < 2; ++ti) {
    const size_t grow = (size_t)(b * kS + qbase + ti * 32 + l31);
#pragma unroll
    for (int ksl = 0; ksl < 4; ++ksl) {
      const char* p = qkvB + grow * kRowB + hOff + ((ksl * 2 + h5) << 4);
      Qh[ti][ksl] = *(const bf16x8*)p;
      Ql[ti][ksl] = *(const bf16x8*)(p + 128);
    }
  }

  f32x16 Oacc[2][2];
#pragma unroll
  for (int a = 0; a < 2; ++a)
#pragma unroll
    for (int d = 0; d < 2; ++d)
#pragma unroll
      for (int i = 0; i < 16; ++i) Oacc[a][d][i] = 0.f;
  float lsA[2] = {0.f, 0.f};

  const int clo = (c > 0) ? c - 1 : 0;
  const int chi = (c < kC - 1) ? c + 1 : kC - 1;
  const int nwin = (chi - clo + 1) * 4;
  const int ntiles = nwin + ((clo != 0) ? 1 : 0);

  U32x4 pa[2][4];

  for (int tt = 0; tt < ntiles; ++tt) {
    const bool isCls = (tt >= nwin);
    const int srow = isCls ? 0 : (clo * kChunk + tt * 64);

    __syncthreads();
#pragma unroll
    for (int j = 0; j < 4; ++j) {
      const int cb = w * 256 + j * 64;     // wave-uniform LDS chunk base
      const int ch = cb + lane;
      const size_t gr = (size_t)(b * kS + srow + (ch >> 3)) * kRowB + ((ch & 7) << 4);
      glds16(qkvB + gr + 3072 + hOff,       &KsH[cb * 8]);
      glds16(qkvB + gr + 6144 + hOff + 128, &VsT[cb * 8]);
    }
    __syncthreads();

#pragma unroll
    for (int kt = 0; kt < 2; ++kt) {
      bf16x8 KH[4];
      const int krow = kt * 32 + l31;
#pragma unroll
      for (int ksl = 0; ksl < 4; ++ksl) {
        const int gg = (((ksl * 2 + h5) ^ (krow & 7)) << 3);
        KH[ksl] = *(const bf16x8*)&KsH[krow * 64 + gg];
      }
#pragma unroll
      for (int ti = 0; ti < 2; ++ti) {
        f32x16 S;
#pragma unroll
        for (int i = 0; i < 16; ++i) S[i] = 0.f;
        __builtin_amdgcn_s_setprio(1);
#pragma unroll
        for (int ksl = 0; ksl < 4; ++ksl) {
          S = __builtin_amdgcn_mfma_f32_32x32x16_bf16(KH[ksl], Qh[ti][ksl], S, 0, 0, 0);
          S = __builtin_amdgcn_mfma_f32_32x32x16_bf16(KH[ksl], Ql[ti][ksl], S, 0, 0, 0);
        }
        __builtin_amdgcn_s_setprio(0);
        unsigned int wpk[4][2], sw[4][2];
        float lacc = 0.f;
#pragma unroll
        for (int m = 0; m < 4; ++m) {
          float e[4];
#pragma unroll
          for (int r = 0; r < 4; ++r) {
            float ev = __expf(S[4 * m + r] * kScale);
            if (isCls && !(kt == 0 && m == 0 && r == 0 && h5 == 0)) ev = 0.f;
            e[r] = ev;
          }
          lacc += (e[0] + e[1]) + (e[2] + e[3]);
          wpk[m][0] = pkbf(e[0], e[1]);
          wpk[m][1] = pkbf(e[2], e[3]);
        }
        lsA[ti] += lacc;
#pragma unroll
        for (int m = 0; m < 4; ++m) {
          sw[m][0] = __shfl_xor(wpk[m][0], 32);
          sw[m][1] = __shfl_xor(wpk[m][1], 32);
        }
#pragma unroll
        for (int jj = 0; jj < 2; ++jj) {
          const int m0 = 2 * jj, m1 = 2 * jj + 1;
          U32x4& P = pa[ti][kt * 2 + jj];
          P.u[0] = h5 ? sw[m1][0]  : wpk[m0][0];
          P.u[1] = h5 ? sw[m1][1]  : wpk[m0][1];
          P.u[2] = h5 ? wpk[m1][0] : sw[m0][0];
          P.u[3] = h5 ? wpk[m1][1] : sw[m0][1];
        }
      }
    }

    __builtin_amdgcn_s_setprio(1);
#pragma unroll
    for (int sl = 0; sl < 4; ++sl) {
#pragma unroll
      for (int dt = 0; dt < 2; ++dt) {
        const int vrow = dt * 32 + l31;
        const bf16x8 vb =
            *(const bf16x8*)&VsT[vrow * 64 + ((((sl * 2 + h5) ^ (vrow & 7))) << 3)];
        Oacc[0][dt] = __builtin_amdgcn_mfma_f32_32x32x16_bf16(pa[0][sl].v, vb, Oacc[0][dt], 0, 0, 0);
        Oacc[1][dt] = __builtin_amdgcn_mfma_f32_32x32x16_bf16(pa[1][sl].v, vb, Oacc[1][dt], 0, 0, 0);
      }
    }
    __builtin_amdgcn_s_setprio(0);
  }

#pragma unroll
  for (int ti = 0; ti < 2; ++ti) {
    float v = lsA[ti];
    v += __shfl_xor(v, 32);
    ls[w][ti * 32 + l31] = v;
  }

#pragma unroll
  for (int ti = 0; ti < 2; ++ti)
#pragma unroll
    for (int m = 0; m < 4; ++m)
#pragma unroll
      for (int r = 0; r < 4; ++r) {
        const int qr = r + 8 * m + 4 * h5;
        const float inv = 1.0f / ls[w][ti * 32 + qr];
        const size_t grow = (size_t)(b * kS + qbase + ti * 32 + qr);
#pragma unroll
        for (int dt = 0; dt < 2; ++dt) {
          const float val = Oacc[ti][dt][4 * m + r] * inv;
          const u16 hb = f2bf(val);
          const size_t o = grow * (size_t)kE + h * 64 + dt * 32 + l31;
          oh[o] = hb;
          ol[o] = f2bf(val - bf2f(hb));
        }
      }
}

}  // namespace

// ---------------------------------------------------------------------------
extern "C" void kernel_launch(void* const* d_in, const int* in_sizes, int n_in,
                              void* d_out, int out_size, void* d_ws, size_t ws_size,
                              hipStream_t stream) {
  const float* x      = (const float*)d_in[0];
  const int*   coords = (const int*)d_in[1];
  const float* Wqkv   = (const float*)d_in[2];
  const float* bqkv   = (const float*)d_in[3];
  const float* Wout   = (const float*)d_in[4];
  const float* bout   = (const float*)d_in[5];
  float* out = (float*)d_out;

  // Workspace (100,663,296 B):
  //   A [0 .. 75,497,472)  packed qkv [B*S][9216B] written by fused QKV GEMM
  //       epilogue (aliased post-attention: WoTh @0)
  //   B [75,497,472 .. +25,165,824)  phase1: WqTh @0; phase2: oh @0,
  //       ol @+12,582,912
  // d_out doubles as scratch (stream-ordered): xh/xl, then cls partials,
  // then the final output overwrites it.
  char* wsb = (char*)d_ws;
  char*  qkvB = wsb;
  u16* WoTh = (u16*)wsb;
  char* rb = wsb + 75497472;
  u16* WqTh = (u16*)rb;
  u16* oh   = (u16*)rb;
  u16* ol   = (u16*)(rb + 12582912);
  u16* xh   = (u16*)d_out;
  u16* xl   = (u16*)((char*)d_out + 12582912);
  float* clsPart = out;

  const int M = kB * kS;  // 8192

  // 1. prep: x pre-split (scratch in d_out) + transpose+bf16 W_qkv
  prep<<<3504, 256, 0, stream>>>(x, xh, xl, Wqkv, WqTh);

  // 2. QKV projection with fused rope/pack/V^T epilogue -> packed qkvB
  {
    const int nwg = (kQKV / 128) * (M / 128);   // 1152, %8==0
    gemm_mfma<true><<<nwg, 256, 0, stream>>>(xh, xl, WqTh, bqkv, nullptr,
                                             qkvB, coords, M, kQKV, kE);
  }

  // 3. Windowed attention (2-term QK^T) + fused CLS partials -> oh/ol, clsPart
  attn_win_mfma<<<960, 128, 0, stream>>>(qkvB, oh, ol, clsPart);

  // 4. tail: transpose+bf16 W_out (dead qkv space) + CLS combine
  wsplit_comb<<<168, 256, 0, stream>>>(Wout, WoTh, clsPart, oh, ol);

  // 5. Output projection (thin 64x128 tiles, 768 blocks)
  {
    const int nwg = (kE / 128) * (M / 64);      // 768, %8==0
    gemm_thin<<<nwg, 256, 0, stream>>>(oh, ol, WoTh, bout, out, M, kE, kE);
  }
}

// Round 22
// 174.547 us; speedup vs baseline: 1.1183x; 1.0170x over previous
//
#include <hip/hip_runtime.h>

namespace {

typedef unsigned short u16;
typedef __bf16 bf16x8 __attribute__((ext_vector_type(8)));
typedef __bf16 bf16x2 __attribute__((ext_vector_type(2)));
typedef float f32x4 __attribute__((ext_vector_type(4)));
typedef float f32x16 __attribute__((ext_vector_type(16)));
typedef u16 u16x8v __attribute__((ext_vector_type(8)));
struct alignas(8) u16x4 { u16 x, y, z, w; };
union U32x4 { unsigned int u[4]; bf16x8 v; };

constexpr int kS    = 4096;
constexpr int kE    = 768;
constexpr int kH    = 12;
constexpr int kD    = 64;
constexpr int kQKV  = 2304;   // 3*E
constexpr int kChunk = 256;
constexpr int kC    = 16;     // S / CHUNK
constexpr int kB    = 2;
constexpr float kScale = 0.125f;  // 1/sqrt(64)
constexpr int kRowB = 9216;       // qkv row bytes
constexpr int kClsSplit = 16;     // key-chunks per (b,h) for CLS attention
constexpr float kL2 = 0.83048202372184058696f;  // log2(10000)/16

// ---- bf16 helpers (RNE) ---------------------------------------------------
__device__ __forceinline__ u16 f2bf(float f) {
  unsigned int u = __float_as_uint(f);
  u += 0x7FFFu + ((u >> 16) & 1u);
  return (u16)(u >> 16);
}
__device__ __forceinline__ float bf2f(u16 h) {
  return __uint_as_float(((unsigned int)h) << 16);
}
// packed pair via casts -> v_cvt_pk_bf16_f32 (RNE, same bits as f2bf here)
__device__ __forceinline__ unsigned int pkbf(float a, float b) {
  bf16x2 p;
  p[0] = (__bf16)a;
  p[1] = (__bf16)b;
  return __builtin_bit_cast(unsigned int, p);
}

// ---- XCD-aware bijective block swizzle (grid % 8 == 0) ---------------------
__device__ __forceinline__ int xcd_swz(int bid, int nwg) {
  const int cpx = nwg >> 3;
  return (bid & 7) * cpx + (bid >> 3);
}

// ---- async global->LDS, 16B per lane --------------------------------------
__device__ __forceinline__ void glds16(const void* g, void* l) {
  __builtin_amdgcn_global_load_lds(
      (const __attribute__((address_space(1))) unsigned int*)g,
      (__attribute__((address_space(3))) unsigned int*)l, 16, 0, 0);
}

// ---------------------------------------------------------------------------
// wsplit body: W[K][N] fp32 -> Th[N][K] bf16 (transposed, hi only).
// ---------------------------------------------------------------------------
__device__ __forceinline__ void wsplit_body(const float* __restrict__ W,
                                            u16* __restrict__ Th, int K, int N,
                                            int bid, int t, float (*tile)[65]) {
  const int ntiles = N >> 6;
  const int n0 = (bid % ntiles) << 6;
  const int k0 = (bid / ntiles) << 6;
  const int r  = t >> 2;
  const int cs = (t & 3) << 4;
  const float* src = W + (size_t)(k0 + r) * N + n0 + cs;
#pragma unroll
  for (int i = 0; i < 4; ++i) {
    float4 v = *(const float4*)(src + 4 * i);
    tile[r][cs + 4 * i + 0] = v.x;
    tile[r][cs + 4 * i + 1] = v.y;
    tile[r][cs + 4 * i + 2] = v.z;
    tile[r][cs + 4 * i + 3] = v.w;
  }
  __syncthreads();
  u16* dh = Th + (size_t)(n0 + r) * K + k0 + cs;
#pragma unroll
  for (int i = 0; i < 4; ++i) {
    u16x4 hq;
    hq.x = f2bf(tile[cs + 4 * i + 0][r]);
    hq.y = f2bf(tile[cs + 4 * i + 1][r]);
    hq.z = f2bf(tile[cs + 4 * i + 2][r]);
    hq.w = f2bf(tile[cs + 4 * i + 3][r]);
    *(u16x4*)(dh + 4 * i) = hq;
  }
}

// ---------------------------------------------------------------------------
// prep: blocks [0,3072) = x pre-split; blocks [3072,3504) = wsplit(W_qkv).
// ---------------------------------------------------------------------------
__global__ __launch_bounds__(256)
void prep(const float* __restrict__ x, u16* __restrict__ xh, u16* __restrict__ xl,
          const float* __restrict__ Wq, u16* __restrict__ WqTh) {
  __shared__ float tile[64][65];
  if (blockIdx.x < 3072) {
    const size_t i8 = ((size_t)blockIdx.x * 256 + threadIdx.x) * 8;
    const float4 v0 = *(const float4*)(x + i8);
    const float4 v1 = *(const float4*)(x + i8 + 4);
    const float f[8] = {v0.x, v0.y, v0.z, v0.w, v1.x, v1.y, v1.z, v1.w};
    u16x8v hv, lv;
#pragma unroll
    for (int j = 0; j < 8; ++j) {
      const u16 hb = f2bf(f[j]);
      hv[j] = hb;
      lv[j] = f2bf(f[j] - bf2f(hb));
    }
    *(u16x8v*)(xh + i8) = hv;
    *(u16x8v*)(xl + i8) = lv;
  } else {
    wsplit_body(Wq, WqTh, kE, kQKV, blockIdx.x - 3072, threadIdx.x, tile);
  }
}

// ---------------------------------------------------------------------------
// tail: blocks [0,144) = wsplit(W_out); blocks [144,168) = cls combine.
// ---------------------------------------------------------------------------
__global__ __launch_bounds__(256)
void wsplit_comb(const float* __restrict__ Wout, u16* __restrict__ WoTh,
                 const float* __restrict__ part,
                 u16* __restrict__ oh, u16* __restrict__ ol) {
  __shared__ float tile[64][65];
  if (blockIdx.x < 144) {
    wsplit_body(Wout, WoTh, kE, kE, blockIdx.x, threadIdx.x, tile);
  } else {
    if (threadIdx.x >= 64) return;
    const int bid = blockIdx.x - 144;      // 0..23
    const int h = bid % kH;
    const int b = bid / kH;
    const int lane = threadIdx.x;
    const float* src = part + (size_t)((b * kH + h) * kClsSplit) * 66;
    float s = 0.f, L = 0.f;
#pragma unroll
    for (int p = 0; p < kClsSplit; ++p) {
      s += src[p * 66 + lane];
      L += src[p * 66 + 64];
    }
    const float v = s / L;
    const u16 hb = f2bf(v);
    const size_t off0 = (size_t)(b * kS) * kE + h * kD + lane;
    oh[off0] = hb;
    ol[off0] = f2bf(v - bf2f(hb));
  }
}

// ---------------------------------------------------------------------------
// Split-bf16 MFMA GEMM: 128x128 tile, 2-term, depth-2 pipelined, LDS
// group-XOR swizzle, fused rope/pack/V^T epilogue (QKV=true).
// NEW (r22): v-sector blocks ((n0>>6)>=24) skip the Al term -- v is truncated
// to bf16 in the epilogue anyway, pre-quant error 5.5e-4 std << v quantum.
// Staging/vmcnt untouched (pipeline identical); only fal reads+MFMAs skipped.
// ---------------------------------------------------------------------------
template <bool QKV>
__global__ __launch_bounds__(256, 2)
void gemm_mfma(const u16* __restrict__ Ahg, const u16* __restrict__ Alg,
               const u16* __restrict__ Bhg,
               const float* __restrict__ bias, float* __restrict__ C,
               char* __restrict__ outPk, const int* __restrict__ coords,
               int M, int N, int K) {
  __shared__ __align__(16) u16 smem[24576];
  u16* AsH = smem;
  u16* AsL = smem + 8192;
  u16* BsH = smem + 16384;

  const int nwg = gridDim.x;
  const int lid = xcd_swz(blockIdx.x, nwg);
  const int nTiles = N >> 7;
  const int m0 = (lid / nTiles) << 7;
  const int n0 = (lid % nTiles) << 7;

  // v-sector: output immediately re-quantized to bf16 -> Al term dropped.
  const bool vsec = QKV && ((n0 >> 6) >= 24);

  const int tid  = threadIdx.x;
  const int wave = tid >> 6;
  const int lane = tid & 63;
  const int l15  = lane & 15;
  const int khf  = lane >> 4;
  const int wm   = wave >> 1;
  const int wn   = wave & 1;

  const int c0 = wave * 2, c1 = wave * 2 + 1;
  const int rr = lane >> 2;
  const int gg = lane & 3;
  const int gsw = gg ^ ((rr >> 1) & 3);          // pre-swizzled source group
  const int kg  = khf ^ ((l15 >> 1) & 3);        // swizzled read slot

  const size_t bOff0 = (size_t)(n0 + c0 * 16 + rr) * K + gsw * 8;
  const size_t bOff1 = (size_t)(n0 + c1 * 16 + rr) * K + gsw * 8;
  const size_t aOff0 = (size_t)(m0 + c0 * 16 + rr) * K + gsw * 8;
  const size_t aOff1 = (size_t)(m0 + c1 * 16 + rr) * K + gsw * 8;

  auto STAGE = [&](int p, int k0) {
    glds16(Bhg + bOff0 + k0, BsH + p * 4096 + (c0 * 16) * 32);
    glds16(Bhg + bOff1 + k0, BsH + p * 4096 + (c1 * 16) * 32);
    glds16(Ahg + aOff0 + k0, AsH + p * 4096 + (c0 * 16) * 32);
    glds16(Ahg + aOff1 + k0, AsH + p * 4096 + (c1 * 16) * 32);
    glds16(Alg + aOff0 + k0, AsL + p * 4096 + (c0 * 16) * 32);
    glds16(Alg + aOff1 + k0, AsL + p * 4096 + (c1 * 16) * 32);
  };

  f32x4 acc[4][4];
#pragma unroll
  for (int i = 0; i < 4; ++i)
#pragma unroll
    for (int j = 0; j < 4; ++j) acc[i][j] = (f32x4){0.f, 0.f, 0.f, 0.f};

  auto COMPUTE = [&](int p) {
    bf16x8 fah[4], fal[4], fbh[4];
#pragma unroll
    for (int f = 0; f < 4; ++f) {
      fah[f] = *(const bf16x8*)&AsH[p * 4096 + (wm * 64 + f * 16 + l15) * 32 + kg * 8];
      fbh[f] = *(const bf16x8*)&BsH[p * 4096 + (wn * 64 + f * 16 + l15) * 32 + kg * 8];
    }
    if (!vsec) {
#pragma unroll
      for (int f = 0; f < 4; ++f)
        fal[f] = *(const bf16x8*)&AsL[p * 4096 + (wm * 64 + f * 16 + l15) * 32 + kg * 8];
    }
#pragma unroll
    for (int mi = 0; mi < 4; ++mi)
#pragma unroll
      for (int ni = 0; ni < 4; ++ni)
        acc[mi][ni] = __builtin_amdgcn_mfma_f32_16x16x32_bf16(fah[mi], fbh[ni], acc[mi][ni], 0, 0, 0);
    if (!vsec) {
#pragma unroll
      for (int mi = 0; mi < 4; ++mi)
#pragma unroll
        for (int ni = 0; ni < 4; ++ni)
          acc[mi][ni] = __builtin_amdgcn_mfma_f32_16x16x32_bf16(fal[mi], fbh[ni], acc[mi][ni], 0, 0, 0);
    }
  };

  STAGE(0, 0);
  STAGE(1, 32);
  int cur = 0;

  for (int k0 = 0; k0 < K - 32; k0 += 32) {
    asm volatile("s_waitcnt vmcnt(6)" ::: "memory");
    __builtin_amdgcn_sched_barrier(0);
    __builtin_amdgcn_s_barrier();

    COMPUTE(cur);

    __builtin_amdgcn_sched_barrier(0);
    asm volatile("s_waitcnt lgkmcnt(0)" ::: "memory");
    __builtin_amdgcn_s_barrier();
    if (k0 + 64 < K) STAGE(cur, k0 + 64);
    cur ^= 1;
  }

  asm volatile("s_waitcnt vmcnt(0)" ::: "memory");
  __builtin_amdgcn_sched_barrier(0);
  __builtin_amdgcn_s_barrier();
  COMPUTE(cur);

  if constexpr (!QKV) {
#pragma unroll
    for (int ni = 0; ni < 4; ++ni) {
      const int col = n0 + wn * 64 + ni * 16 + l15;
      const float bv = bias[col];
#pragma unroll
      for (int mi = 0; mi < 4; ++mi) {
        const int rbase = m0 + wm * 64 + mi * 16 + khf * 4;
#pragma unroll
        for (int r = 0; r < 4; ++r)
          C[(size_t)(rbase + r) * N + col] = acc[mi][ni][r] + bv;
      }
    }
  } else {
    __syncthreads();   // all LDS staging reads done; smem free for bounce

    const int col64  = (n0 >> 6) + wn;   // 0..35
    const int sector = col64 / 12;       // 0=q, 1=k, 2=v
    const int hh     = col64 % 12;
    const int rowbase = m0 + wm * 64;    // 64-aligned

    if (sector < 2) {
      const int sel = sector;
#pragma unroll
      for (int mi = 0; mi < 4; ++mi)
#pragma unroll
        for (int r = 0; r < 4; ++r) {
          const int row = rowbase + mi * 16 + khf * 4 + r;
          const int bb = row >> 12;
          const int ss = row & 4095;
          float cx = 0.f, cy = 0.f;
          if (ss >= 1) {
            const size_t ci = ((size_t)bb * (kS - 1) + (ss - 1)) * 2;
            cx = (float)coords[ci]     * (1.0f / 100000.0f);
            cy = (float)coords[ci + 1] * (1.0f / 100000.0f);
          }
          const int swz = (sel == 1) ? (ss & 7) : 0;
          char* base = outPk + (size_t)row * kRowB + sel * 3072 + hh * 256;
#pragma unroll
          for (int ni = 0; ni < 4; ++ni) {
            const int d = ni * 16 + l15;
            const float v0 = acc[mi][ni][r] + bias[n0 + wn * 64 + ni * 16 + l15];
            const float pv = __shfl_xor(v0, 1);   // partner d^1 (all lanes exec)
            float nv = v0;
            if (ss >= 1) {
              const float coord = (d < 32) ? cx : cy;
              const float ang = coord * exp2f(-(float)((d >> 1) & 15) * kL2);
              const float sn = __sinf(ang), cn = __cosf(ang);
              nv = (d & 1) ? fmaf(v0, cn, pv * sn) : fmaf(v0, cn, -pv * sn);
            }
            const u16 hb = f2bf(nv);
            const u16 lb = f2bf(nv - bf2f(hb));
            const int gofs = (((d >> 3) ^ swz) << 4) + (d & 7) * 2;
            *(u16*)(base + gofs) = hb;
            *(u16*)(base + 128 + gofs) = lb;
          }
        }
    } else {
      u16* ldsT = smem + wave * 4352;    // 64 x 68 u16 per wave (8.5 KB)
#pragma unroll
      for (int mi = 0; mi < 4; ++mi)
#pragma unroll
        for (int ni = 0; ni < 4; ++ni)
#pragma unroll
          for (int r = 0; r < 4; ++r) {
            const int key = mi * 16 + khf * 4 + r;   // row within 64-group
            const int row = rowbase + key;
            const int d = ni * 16 + l15;
            const float v0 = acc[mi][ni][r] + bias[n0 + wn * 64 + ni * 16 + l15];
            const u16 hb = f2bf(v0);
            *(u16*)(outPk + (size_t)row * kRowB + 6144 + hh * 256 + d * 2) = hb;
            ldsT[d * 68 + key] = hb;
          }
      const int dd = lane;               // V^T row = d
      char* vbase = outPk + (size_t)(rowbase + dd) * kRowB + 6144 + hh * 256 + 128;
#pragma unroll
      for (int kgx = 0; kgx < 8; ++kgx) {
        const u16x4 a0 = *(const u16x4*)&ldsT[dd * 68 + kgx * 8];
        const u16x4 a1 = *(const u16x4*)&ldsT[dd * 68 + kgx * 8 + 4];
        char* dst = vbase + ((kgx ^ (dd & 7)) << 4);
        *(u16x4*)dst = a0;
        *(u16x4*)(dst + 8) = a1;
      }
    }
  }
}

// ---------------------------------------------------------------------------
// Thin GEMM for out-projection (round-17 proven): 64x128 tile, depth-2
// pipelined, LDS group-XOR swizzle. Full 2-term (o-lo matters here).
// ---------------------------------------------------------------------------
__global__ __launch_bounds__(256, 2)
void gemm_thin(const u16* __restrict__ Ahg, const u16* __restrict__ Alg,
               const u16* __restrict__ Bhg,
               const float* __restrict__ bias, float* __restrict__ C,
               int M, int N, int K) {
  __shared__ __align__(16) u16 smem[16384];   // 2 x (Ah 2048 | Al 2048 | B 4096)
  const int nwg = gridDim.x;
  const int lid = xcd_swz(blockIdx.x, nwg);
  const int nTiles = N >> 7;
  const int m0 = (lid / nTiles) << 6;
  const int n0 = (lid % nTiles) << 7;

  const int tid  = threadIdx.x;
  const int wave = tid >> 6;
  const int lane = tid & 63;
  const int l15  = lane & 15;
  const int khf  = lane >> 4;

  const int rr = lane >> 2;
  const int gg = lane & 3;
  const int gsw = gg ^ ((rr >> 1) & 3);
  const int kg  = khf ^ ((l15 >> 1) & 3);

  const size_t aOff  = (size_t)(m0 + wave * 16 + rr) * K + gsw * 8;
  const size_t bOff0 = (size_t)(n0 + (2 * wave) * 16 + rr) * K + gsw * 8;
  const size_t bOff1 = (size_t)(n0 + (2 * wave + 1) * 16 + rr) * K + gsw * 8;

  auto STAGE = [&](int p, int k0) {
    u16* base = smem + p * 8192;
    glds16(Ahg + aOff + k0,  base + (wave * 16) * 32);
    glds16(Alg + aOff + k0,  base + 2048 + (wave * 16) * 32);
    glds16(Bhg + bOff0 + k0, base + 4096 + (2 * wave * 16) * 32);
    glds16(Bhg + bOff1 + k0, base + 4096 + ((2 * wave + 1) * 16) * 32);
  };

  f32x4 acc[4][2];
#pragma unroll
  for (int i = 0; i < 4; ++i)
#pragma unroll
    for (int j = 0; j < 2; ++j) acc[i][j] = (f32x4){0.f, 0.f, 0.f, 0.f};

  auto COMPUTE = [&](int p) {
    u16* base = smem + p * 8192;
    bf16x8 fah[4], fal[4], fbh[2];
#pragma unroll
    for (int f = 0; f < 4; ++f) {
      fah[f] = *(const bf16x8*)&base[(f * 16 + l15) * 32 + kg * 8];
      fal[f] = *(const bf16x8*)&base[2048 + (f * 16 + l15) * 32 + kg * 8];
    }
#pragma unroll
    for (int f = 0; f < 2; ++f)
      fbh[f] = *(const bf16x8*)&base[4096 + (wave * 32 + f * 16 + l15) * 32 + kg * 8];
#pragma unroll
    for (int mi = 0; mi < 4; ++mi)
#pragma unroll
      for (int ni = 0; ni < 2; ++ni)
        acc[mi][ni] = __builtin_amdgcn_mfma_f32_16x16x32_bf16(fah[mi], fbh[ni], acc[mi][ni], 0, 0, 0);
#pragma unroll
    for (int mi = 0; mi < 4; ++mi)
#pragma unroll
      for (int ni = 0; ni < 2; ++ni)
        acc[mi][ni] = __builtin_amdgcn_mfma_f32_16x16x32_bf16(fal[mi], fbh[ni], acc[mi][ni], 0, 0, 0);
  };

  STAGE(0, 0);
  STAGE(1, 32);
  int cur = 0;

  for (int k0 = 0; k0 < K - 32; k0 += 32) {
    asm volatile("s_waitcnt vmcnt(4)" ::: "memory");
    __builtin_amdgcn_sched_barrier(0);
    __builtin_amdgcn_s_barrier();

    COMPUTE(cur);

    __builtin_amdgcn_sched_barrier(0);
    asm volatile("s_waitcnt lgkmcnt(0)" ::: "memory");
    __builtin_amdgcn_s_barrier();
    if (k0 + 64 < K) STAGE(cur, k0 + 64);
    cur ^= 1;
  }

  asm volatile("s_waitcnt vmcnt(0)" ::: "memory");
  __builtin_amdgcn_sched_barrier(0);
  __builtin_amdgcn_s_barrier();
  COMPUTE(cur);

#pragma unroll
  for (int ni = 0; ni < 2; ++ni) {
    const int col = n0 + wave * 32 + ni * 16 + l15;
    const float bv = bias[col];
#pragma unroll
    for (int mi = 0; mi < 4; ++mi) {
      const int rbase = m0 + mi * 16 + khf * 4;
#pragma unroll
      for (int r = 0; r < 4; ++r)
        C[(size_t)(rbase + r) * N + col] = acc[mi][ni][r] + bv;
    }
  }
}

// ---------------------------------------------------------------------------
// Windowed attention + fused CLS partials. Grid = 768 attn + 192 cls = 960.
// r21: QK^T K-lo dropped. NEW (r22): Q-lo dropped too (pure bf16 QK^T;
// logit error ~2.8e-4 scaled, O error ~2e-5 after softmax averaging).
// 16 QK^T MFMAs/tile, 8 glds/wave/tile, LDS 16.9 KB.
// ---------------------------------------------------------------------------
__global__ __launch_bounds__(128)
void attn_win_mfma(const char* __restrict__ qkvB,
                   u16* __restrict__ oh, u16* __restrict__ ol,
                   float* __restrict__ part) {
  __shared__ __align__(16) u16 sm[8448];   // 16.9 KB
  __shared__ float ls[2][64];

  const int idx  = xcd_swz(blockIdx.x, gridDim.x);
  const int tid  = threadIdx.x;
  const int w    = tid >> 6;           // 0..1
  const int lane = tid & 63;

  if (idx >= 768) {
    // ================= CLS partial (one 256-key chunk per wave) ============
    const int chunk = (idx - 768) * 2 + w;      // 0..383
    const int p = chunk & (kClsSplit - 1);
    const int h = (chunk >> 4) % kH;
    const int b = chunk / (kClsSplit * kH);
    const int hOff = h * 256;
    const int keysPer = kS / kClsSplit;         // 256
    float* obuf = (float*)sm + w * 2112;        // [64][33] per wave (8.4 KB)

    float q[64];
    {
      const char* qp = qkvB + (size_t)(b * kS) * kRowB + hOff;
#pragma unroll
      for (int g = 0; g < 8; ++g) {
        const u16x8v hv = *(const u16x8v*)(qp + (g << 4));
        const u16x8v lv = *(const u16x8v*)(qp + 128 + (g << 4));
#pragma unroll
        for (int j = 0; j < 8; ++j) q[g * 8 + j] = bf2f(hv[j]) + bf2f(lv[j]);
      }
    }

    float oacc[64] = {};
    float l = 0.f;
    for (int i = 0; i < keysPer / 64; ++i) {
      const int sk = p * keysPer + i * 64 + lane;
      const char* rp = qkvB + (size_t)(b * kS + sk) * kRowB;
      const int swz = sk & 7;
      float dp = 0.f;
#pragma unroll
      for (int g = 0; g < 8; ++g) {
        const char* kp = rp + 3072 + hOff + ((g ^ swz) << 4);
        const u16x8v kh = *(const u16x8v*)kp;
        const u16x8v kl = *(const u16x8v*)(kp + 128);
#pragma unroll
        for (int j = 0; j < 8; ++j)
          dp = fmaf(q[g * 8 + j], bf2f(kh[j]) + bf2f(kl[j]), dp);
      }
      const float e = __expf(dp * kScale);
      l += e;
      const char* vp = rp + 6144 + hOff;
#pragma unroll
      for (int g = 0; g < 8; ++g) {
        const u16x8v vv = *(const u16x8v*)(vp + (g << 4));
#pragma unroll
        for (int j = 0; j < 8; ++j)
          oacc[g * 8 + j] = fmaf(e, bf2f(vv[j]), oacc[g * 8 + j]);
      }
    }

    float L = l;
#pragma unroll
    for (int off = 32; off > 0; off >>= 1) L += __shfl_xor(L, off);

    // two-pass cross-lane transpose-sum in 8.4 KB (wave-local; explicit fences)
    float sum = 0.f;
#pragma unroll
    for (int pass = 0; pass < 2; ++pass) {
#pragma unroll
      for (int d = 0; d < 32; ++d) obuf[lane * 33 + d] = oacc[pass * 32 + d];
      asm volatile("s_waitcnt lgkmcnt(0)" ::: "memory");
      __builtin_amdgcn_sched_barrier(0);
      if ((lane >> 5) == pass) {
        const int cc = lane & 31;
        for (int ln = 0; ln < 64; ++ln) sum += obuf[ln * 33 + cc];
      }
      asm volatile("s_waitcnt lgkmcnt(0)" ::: "memory");
      __builtin_amdgcn_sched_barrier(0);
    }

    float* dst = part + (size_t)chunk * 66;
    dst[lane] = sum;
    if (lane == 0) dst[64] = L;
    return;
  }

  // ================= windowed attention (pure bf16 QK^T) ==================
  u16* KsH = sm;
  u16* VsT = sm + 4096;

  const int half = idx & 1;
  const int c = (idx >> 1) % kC;
  const int h = ((idx >> 1) / kC) % kH;
  const int b = idx / (2 * kC * kH);
  const int l31  = lane & 31;
  const int h5   = lane >> 5;
  const int hOff = h * 256;
  const int qbase = c * kChunk + half * 128 + w * 64;

  bf16x8 Qh[2][4];
#pragma unroll
  for (int ti = 0; ti < 2; ++ti) {
    const size_t grow = (size_t)(b * kS + qbase + ti * 32 + l31);
#pragma unroll
    for (int ksl = 0; ksl < 4; ++ksl) {
      const char* p = qkvB + grow * kRowB + hOff + ((ksl * 2 + h5) << 4);
      Qh[ti][ksl] = *(const bf16x8*)p;
    }
  }

  f32x16 Oacc[2][2];
#pragma unroll
  for (int a = 0; a < 2; ++a)
#pragma unroll
    for (int d = 0; d < 2; ++d)
#pragma unroll
      for (int i = 0; i < 16; ++i) Oacc[a][d][i] = 0.f;
  float lsA[2] = {0.f, 0.f};

  const int clo = (c > 0) ? c - 1 : 0;
  const int chi = (c < kC - 1) ? c + 1 : kC - 1;
  const int nwin = (chi - clo + 1) * 4;
  const int ntiles = nwin + ((clo != 0) ? 1 : 0);

  U32x4 pa[2][4];

  for (int tt = 0; tt < ntiles; ++tt) {
    const bool isCls = (tt >= nwin);
    const int srow = isCls ? 0 : (clo * kChunk + tt * 64);

    __syncthreads();
#pragma unroll
    for (int j = 0; j < 4; ++j) {
      const int cb = w * 256 + j * 64;     // wave-uniform LDS chunk base
      const int ch = cb + lane;
      const size_t gr = (size_t)(b * kS + srow + (ch >> 3)) * kRowB + ((ch & 7) << 4);
      glds16(qkvB + gr + 3072 + hOff,       &KsH[cb * 8]);
      glds16(qkvB + gr + 6144 + hOff + 128, &VsT[cb * 8]);
    }
    __syncthreads();

#pragma unroll
    for (int kt = 0; kt < 2; ++kt) {
      bf16x8 KH[4];
      const int krow = kt * 32 + l31;
#pragma unroll
      for (int ksl = 0; ksl < 4; ++ksl) {
        const int gg = (((ksl * 2 + h5) ^ (krow & 7)) << 3);
        KH[ksl] = *(const bf16x8*)&KsH[krow * 64 + gg];
      }
#pragma unroll
      for (int ti = 0; ti < 2; ++ti) {
        f32x16 S;
#pragma unroll
        for (int i = 0; i < 16; ++i) S[i] = 0.f;
        __builtin_amdgcn_s_setprio(1);
#pragma unroll
        for (int ksl = 0; ksl < 4; ++ksl)
          S = __builtin_amdgcn_mfma_f32_32x32x16_bf16(KH[ksl], Qh[ti][ksl], S, 0, 0, 0);
        __builtin_amdgcn_s_setprio(0);
        unsigned int wpk[4][2], sw[4][2];
        float lacc = 0.f;
#pragma unroll
        for (int m = 0; m < 4; ++m) {
          float e[4];
#pragma unroll
          for (int r = 0; r < 4; ++r) {
            float ev = __expf(S[4 * m + r] * kScale);
            if (isCls && !(kt == 0 && m == 0 && r == 0 && h5 == 0)) ev = 0.f;
            e[r] = ev;
          }
          lacc += (e[0] + e[1]) + (e[2] + e[3]);
          wpk[m][0] = pkbf(e[0], e[1]);
          wpk[m][1] = pkbf(e[2], e[3]);
        }
        lsA[ti] += lacc;
#pragma unroll
        for (int m = 0; m < 4; ++m) {
          sw[m][0] = __shfl_xor(wpk[m][0], 32);
          sw[m][1] = __shfl_xor(wpk[m][1], 32);
        }
#pragma unroll
        for (int jj = 0; jj < 2; ++jj) {
          const int m0 = 2 * jj, m1 = 2 * jj + 1;
          U32x4& P = pa[ti][kt * 2 + jj];
          P.u[0] = h5 ? sw[m1][0]  : wpk[m0][0];
          P.u[1] = h5 ? sw[m1][1]  : wpk[m0][1];
          P.u[2] = h5 ? wpk[m1][0] : sw[m0][0];
          P.u[3] = h5 ? wpk[m1][1] : sw[m0][1];
        }
      }
    }

    __builtin_amdgcn_s_setprio(1);
#pragma unroll
    for (int sl = 0; sl < 4; ++sl) {
#pragma unroll
      for (int dt = 0; dt < 2; ++dt) {
        const int vrow = dt * 32 + l31;
        const bf16x8 vb =
            *(const bf16x8*)&VsT[vrow * 64 + ((((sl * 2 + h5) ^ (vrow & 7))) << 3)];
        Oacc[0][dt] = __builtin_amdgcn_mfma_f32_32x32x16_bf16(pa[0][sl].v, vb, Oacc[0][dt], 0, 0, 0);
        Oacc[1][dt] = __builtin_amdgcn_mfma_f32_32x32x16_bf16(pa[1][sl].v, vb, Oacc[1][dt], 0, 0, 0);
      }
    }
    __builtin_amdgcn_s_setprio(0);
  }

#pragma unroll
  for (int ti = 0; ti < 2; ++ti) {
    float v = lsA[ti];
    v += __shfl_xor(v, 32);
    ls[w][ti * 32 + l31] = v;
  }

#pragma unroll
  for (int ti = 0; ti < 2; ++ti)
#pragma unroll
    for (int m = 0; m < 4; ++m)
#pragma unroll
      for (int r = 0; r < 4; ++r) {
        const int qr = r + 8 * m + 4 * h5;
        const float inv = 1.0f / ls[w][ti * 32 + qr];
        const size_t grow = (size_t)(b * kS + qbase + ti * 32 + qr);
#pragma unroll
        for (int dt = 0; dt < 2; ++dt) {
          const float val = Oacc[ti][dt][4 * m + r] * inv;
          const u16 hb = f2bf(val);
          const size_t o = grow * (size_t)kE + h * 64 + dt * 32 + l31;
          oh[o] = hb;
          ol[o] = f2bf(val - bf2f(hb));
        }
      }
}

}  // namespace

// ---------------------------------------------------------------------------
extern "C" void kernel_launch(void* const* d_in, const int* in_sizes, int n_in,
                              void* d_out, int out_size, void* d_ws, size_t ws_size,
                              hipStream_t stream) {
  const float* x      = (const float*)d_in[0];
  const int*   coords = (const int*)d_in[1];
  const float* Wqkv   = (const float*)d_in[2];
  const float* bqkv   = (const float*)d_in[3];
  const float* Wout   = (const float*)d_in[4];
  const float* bout   = (const float*)d_in[5];
  float* out = (float*)d_out;

  // Workspace (100,663,296 B):
  //   A [0 .. 75,497,472)  packed qkv [B*S][9216B] written by fused QKV GEMM
  //       epilogue (aliased post-attention: WoTh @0)
  //   B [75,497,472 .. +25,165,824)  phase1: WqTh @0; phase2: oh @0,
  //       ol @+12,582,912
  // d_out doubles as scratch (stream-ordered): xh/xl, then cls partials,
  // then the final output overwrites it.
  char* wsb = (char*)d_ws;
  char*  qkvB = wsb;
  u16* WoTh = (u16*)wsb;
  char* rb = wsb + 75497472;
  u16* WqTh = (u16*)rb;
  u16* oh   = (u16*)rb;
  u16* ol   = (u16*)(rb + 12582912);
  u16* xh   = (u16*)d_out;
  u16* xl   = (u16*)((char*)d_out + 12582912);
  float* clsPart = out;

  const int M = kB * kS;  // 8192

  // 1. prep: x pre-split (scratch in d_out) + transpose+bf16 W_qkv
  prep<<<3504, 256, 0, stream>>>(x, xh, xl, Wqkv, WqTh);

  // 2. QKV projection with fused rope/pack/V^T epilogue -> packed qkvB
  {
    const int nwg = (kQKV / 128) * (M / 128);   // 1152, %8==0
    gemm_mfma<true><<<nwg, 256, 0, stream>>>(xh, xl, WqTh, bqkv, nullptr,
                                             qkvB, coords, M, kQKV, kE);
  }

  // 3. Windowed attention (bf16 QK^T) + fused CLS partials -> oh/ol, clsPart
  attn_win_mfma<<<960, 128, 0, stream>>>(qkvB, oh, ol, clsPart);

  // 4. tail: transpose+bf16 W_out (dead qkv space) + CLS combine
  wsplit_comb<<<168, 256, 0, stream>>>(Wout, WoTh, clsPart, oh, ol);

  // 5. Output projection (thin 64x128 tiles, 768 blocks)
  {
    const int nwg = (kE / 128) * (M / 64);      // 768, %8==0
    gemm_thin<<<nwg, 256, 0, stream>>>(oh, ol, WoTh, bout, out, M, kE, kE);
  }
}

// Round 23
// 156.085 us; speedup vs baseline: 1.2505x; 1.1183x over previous
//
#include <hip/hip_runtime.h>

namespace {

typedef unsigned short u16;
typedef __bf16 bf16x8 __attribute__((ext_vector_type(8)));
typedef __bf16 bf16x2 __attribute__((ext_vector_type(2)));
typedef float f32x4 __attribute__((ext_vector_type(4)));
typedef float f32x16 __attribute__((ext_vector_type(16)));
typedef u16 u16x8v __attribute__((ext_vector_type(8)));
struct alignas(8) u16x4 { u16 x, y, z, w; };
union U32x4 { unsigned int u[4]; bf16x8 v; };

constexpr int kS    = 4096;
constexpr int kE    = 768;
constexpr int kH    = 12;
constexpr int kD    = 64;
constexpr int kQKV  = 2304;   // 3*E
constexpr int kChunk = 256;
constexpr int kC    = 16;     // S / CHUNK
constexpr int kB    = 2;
constexpr float kScale = 0.125f;  // 1/sqrt(64)
constexpr int kRowB = 9216;       // qkv row bytes
constexpr int kClsSplit = 16;     // key-chunks per (b,h) for CLS attention
constexpr float kL2 = 0.83048202372184058696f;  // log2(10000)/16

// ---- bf16 helpers (RNE) ---------------------------------------------------
__device__ __forceinline__ u16 f2bf(float f) {
  unsigned int u = __float_as_uint(f);
  u += 0x7FFFu + ((u >> 16) & 1u);
  return (u16)(u >> 16);
}
__device__ __forceinline__ float bf2f(u16 h) {
  return __uint_as_float(((unsigned int)h) << 16);
}
// packed pair via casts -> v_cvt_pk_bf16_f32 (RNE, same bits as f2bf here)
__device__ __forceinline__ unsigned int pkbf(float a, float b) {
  bf16x2 p;
  p[0] = (__bf16)a;
  p[1] = (__bf16)b;
  return __builtin_bit_cast(unsigned int, p);
}

// ---- XCD-aware bijective block swizzle (grid % 8 == 0) ---------------------
__device__ __forceinline__ int xcd_swz(int bid, int nwg) {
  const int cpx = nwg >> 3;
  return (bid & 7) * cpx + (bid >> 3);
}

// ---- async global->LDS, 16B per lane --------------------------------------
__device__ __forceinline__ void glds16(const void* g, void* l) {
  __builtin_amdgcn_global_load_lds(
      (const __attribute__((address_space(1))) unsigned int*)g,
      (__attribute__((address_space(3))) unsigned int*)l, 16, 0, 0);
}

// ---------------------------------------------------------------------------
// wsplit body: W[K][N] fp32 -> Th[N][K] bf16 (transposed, hi only).
// ---------------------------------------------------------------------------
__device__ __forceinline__ void wsplit_body(const float* __restrict__ W,
                                            u16* __restrict__ Th, int K, int N,
                                            int bid, int t, float (*tile)[65]) {
  const int ntiles = N >> 6;
  const int n0 = (bid % ntiles) << 6;
  const int k0 = (bid / ntiles) << 6;
  const int r  = t >> 2;
  const int cs = (t & 3) << 4;
  const float* src = W + (size_t)(k0 + r) * N + n0 + cs;
#pragma unroll
  for (int i = 0; i < 4; ++i) {
    float4 v = *(const float4*)(src + 4 * i);
    tile[r][cs + 4 * i + 0] = v.x;
    tile[r][cs + 4 * i + 1] = v.y;
    tile[r][cs + 4 * i + 2] = v.z;
    tile[r][cs + 4 * i + 3] = v.w;
  }
  __syncthreads();
  u16* dh = Th + (size_t)(n0 + r) * K + k0 + cs;
#pragma unroll
  for (int i = 0; i < 4; ++i) {
    u16x4 hq;
    hq.x = f2bf(tile[cs + 4 * i + 0][r]);
    hq.y = f2bf(tile[cs + 4 * i + 1][r]);
    hq.z = f2bf(tile[cs + 4 * i + 2][r]);
    hq.w = f2bf(tile[cs + 4 * i + 3][r]);
    *(u16x4*)(dh + 4 * i) = hq;
  }
}

// ---------------------------------------------------------------------------
// prep: blocks [0,3072) = x -> bf16 hi only (r23: lo term dropped);
//       blocks [3072,3504) = wsplit(W_qkv).
// ---------------------------------------------------------------------------
__global__ __launch_bounds__(256)
void prep(const float* __restrict__ x, u16* __restrict__ xh,
          const float* __restrict__ Wq, u16* __restrict__ WqTh) {
  __shared__ float tile[64][65];
  if (blockIdx.x < 3072) {
    const size_t i8 = ((size_t)blockIdx.x * 256 + threadIdx.x) * 8;
    const float4 v0 = *(const float4*)(x + i8);
    const float4 v1 = *(const float4*)(x + i8 + 4);
    const float f[8] = {v0.x, v0.y, v0.z, v0.w, v1.x, v1.y, v1.z, v1.w};
    u16x8v hv;
#pragma unroll
    for (int j = 0; j < 8; ++j) hv[j] = f2bf(f[j]);
    *(u16x8v*)(xh + i8) = hv;
  } else {
    wsplit_body(Wq, WqTh, kE, kQKV, blockIdx.x - 3072, threadIdx.x, tile);
  }
}

// ---------------------------------------------------------------------------
// tail: blocks [0,144) = wsplit(W_out); blocks [144,168) = cls combine.
// ---------------------------------------------------------------------------
__global__ __launch_bounds__(256)
void wsplit_comb(const float* __restrict__ Wout, u16* __restrict__ WoTh,
                 const float* __restrict__ part,
                 u16* __restrict__ oh, u16* __restrict__ ol) {
  __shared__ float tile[64][65];
  if (blockIdx.x < 144) {
    wsplit_body(Wout, WoTh, kE, kE, blockIdx.x, threadIdx.x, tile);
  } else {
    if (threadIdx.x >= 64) return;
    const int bid = blockIdx.x - 144;      // 0..23
    const int h = bid % kH;
    const int b = bid / kH;
    const int lane = threadIdx.x;
    const float* src = part + (size_t)((b * kH + h) * kClsSplit) * 66;
    float s = 0.f, L = 0.f;
#pragma unroll
    for (int p = 0; p < kClsSplit; ++p) {
      s += src[p * 66 + lane];
      L += src[p * 66 + 64];
    }
    const float v = s / L;
    const u16 hb = f2bf(v);
    const size_t off0 = (size_t)(b * kS) * kE + h * kD + lane;
    oh[off0] = hb;
    ol[off0] = f2bf(v - bf2f(hb));
  }
}

// ---------------------------------------------------------------------------
// QKV GEMM (r23): pure-bf16 A (x-lo dropped everywhere -- qkv error 3e-4 std,
// sub-quantum downstream). 128x128 tile, depth-2 pipelined (4 glds/stage,
// vmcnt(4)), LDS group-XOR swizzle, fused rope/pack/V^T epilogue.
// LDS: AsH 2x4096 | BsH 2x4096 = 32 KB; epilogue ldsT needs 34.8 KB total.
// ---------------------------------------------------------------------------
__global__ __launch_bounds__(256, 2)
void gemm_qkv(const u16* __restrict__ Ahg, const u16* __restrict__ Bhg,
              const float* __restrict__ bias, char* __restrict__ outPk,
              const int* __restrict__ coords, int M, int N, int K) {
  __shared__ __align__(16) u16 smem[17408];   // 34.8 KB (epilogue bounce)
  u16* AsH = smem;            // 2 x 4096
  u16* BsH = smem + 8192;     // 2 x 4096

  const int nwg = gridDim.x;
  const int lid = xcd_swz(blockIdx.x, nwg);
  const int nTiles = N >> 7;
  const int m0 = (lid / nTiles) << 7;
  const int n0 = (lid % nTiles) << 7;

  const int tid  = threadIdx.x;
  const int wave = tid >> 6;
  const int lane = tid & 63;
  const int l15  = lane & 15;
  const int khf  = lane >> 4;
  const int wm   = wave >> 1;
  const int wn   = wave & 1;

  const int c0 = wave * 2, c1 = wave * 2 + 1;
  const int rr = lane >> 2;
  const int gg = lane & 3;
  const int gsw = gg ^ ((rr >> 1) & 3);          // pre-swizzled source group
  const int kg  = khf ^ ((l15 >> 1) & 3);        // swizzled read slot

  const size_t bOff0 = (size_t)(n0 + c0 * 16 + rr) * K + gsw * 8;
  const size_t bOff1 = (size_t)(n0 + c1 * 16 + rr) * K + gsw * 8;
  const size_t aOff0 = (size_t)(m0 + c0 * 16 + rr) * K + gsw * 8;
  const size_t aOff1 = (size_t)(m0 + c1 * 16 + rr) * K + gsw * 8;

  auto STAGE = [&](int p, int k0) {
    glds16(Bhg + bOff0 + k0, BsH + p * 4096 + (c0 * 16) * 32);
    glds16(Bhg + bOff1 + k0, BsH + p * 4096 + (c1 * 16) * 32);
    glds16(Ahg + aOff0 + k0, AsH + p * 4096 + (c0 * 16) * 32);
    glds16(Ahg + aOff1 + k0, AsH + p * 4096 + (c1 * 16) * 32);
  };

  f32x4 acc[4][4];
#pragma unroll
  for (int i = 0; i < 4; ++i)
#pragma unroll
    for (int j = 0; j < 4; ++j) acc[i][j] = (f32x4){0.f, 0.f, 0.f, 0.f};

  auto COMPUTE = [&](int p) {
    bf16x8 fah[4], fbh[4];
#pragma unroll
    for (int f = 0; f < 4; ++f) {
      fah[f] = *(const bf16x8*)&AsH[p * 4096 + (wm * 64 + f * 16 + l15) * 32 + kg * 8];
      fbh[f] = *(const bf16x8*)&BsH[p * 4096 + (wn * 64 + f * 16 + l15) * 32 + kg * 8];
    }
#pragma unroll
    for (int mi = 0; mi < 4; ++mi)
#pragma unroll
      for (int ni = 0; ni < 4; ++ni)
        acc[mi][ni] = __builtin_amdgcn_mfma_f32_16x16x32_bf16(fah[mi], fbh[ni], acc[mi][ni], 0, 0, 0);
  };

  STAGE(0, 0);
  STAGE(1, 32);
  int cur = 0;

  for (int k0 = 0; k0 < K - 32; k0 += 32) {
    asm volatile("s_waitcnt vmcnt(4)" ::: "memory");
    __builtin_amdgcn_sched_barrier(0);
    __builtin_amdgcn_s_barrier();

    COMPUTE(cur);

    __builtin_amdgcn_sched_barrier(0);
    asm volatile("s_waitcnt lgkmcnt(0)" ::: "memory");
    __builtin_amdgcn_s_barrier();
    if (k0 + 64 < K) STAGE(cur, k0 + 64);
    cur ^= 1;
  }

  asm volatile("s_waitcnt vmcnt(0)" ::: "memory");
  __builtin_amdgcn_sched_barrier(0);
  __builtin_amdgcn_s_barrier();
  COMPUTE(cur);

  // ---- fused epilogue (r14-proven): rope/pack q,k; bf16 + V^T for v ----
  __syncthreads();   // all LDS staging reads done; smem free for bounce

  const int col64  = (n0 >> 6) + wn;   // 0..35
  const int sector = col64 / 12;       // 0=q, 1=k, 2=v
  const int hh     = col64 % 12;
  const int rowbase = m0 + wm * 64;    // 64-aligned

  if (sector < 2) {
    const int sel = sector;
#pragma unroll
    for (int mi = 0; mi < 4; ++mi)
#pragma unroll
      for (int r = 0; r < 4; ++r) {
        const int row = rowbase + mi * 16 + khf * 4 + r;
        const int bb = row >> 12;
        const int ss = row & 4095;
        float cx = 0.f, cy = 0.f;
        if (ss >= 1) {
          const size_t ci = ((size_t)bb * (kS - 1) + (ss - 1)) * 2;
          cx = (float)coords[ci]     * (1.0f / 100000.0f);
          cy = (float)coords[ci + 1] * (1.0f / 100000.0f);
        }
        const int swz = (sel == 1) ? (ss & 7) : 0;
        char* base = outPk + (size_t)row * kRowB + sel * 3072 + hh * 256;
#pragma unroll
        for (int ni = 0; ni < 4; ++ni) {
          const int d = ni * 16 + l15;
          const float v0 = acc[mi][ni][r] + bias[n0 + wn * 64 + ni * 16 + l15];
          const float pv = __shfl_xor(v0, 1);   // partner d^1 (all lanes exec)
          float nv = v0;
          if (ss >= 1) {
            const float coord = (d < 32) ? cx : cy;
            const float ang = coord * exp2f(-(float)((d >> 1) & 15) * kL2);
            const float sn = __sinf(ang), cn = __cosf(ang);
            nv = (d & 1) ? fmaf(v0, cn, pv * sn) : fmaf(v0, cn, -pv * sn);
          }
          const u16 hb = f2bf(nv);
          const u16 lb = f2bf(nv - bf2f(hb));
          const int gofs = (((d >> 3) ^ swz) << 4) + (d & 7) * 2;
          *(u16*)(base + gofs) = hb;
          *(u16*)(base + 128 + gofs) = lb;
        }
      }
  } else {
    u16* ldsT = smem + wave * 4352;    // 64 x 68 u16 per wave (8.5 KB)
#pragma unroll
    for (int mi = 0; mi < 4; ++mi)
#pragma unroll
      for (int ni = 0; ni < 4; ++ni)
#pragma unroll
        for (int r = 0; r < 4; ++r) {
          const int key = mi * 16 + khf * 4 + r;   // row within 64-group
          const int row = rowbase + key;
          const int d = ni * 16 + l15;
          const float v0 = acc[mi][ni][r] + bias[n0 + wn * 64 + ni * 16 + l15];
          const u16 hb = f2bf(v0);
          *(u16*)(outPk + (size_t)row * kRowB + 6144 + hh * 256 + d * 2) = hb;
          ldsT[d * 68 + key] = hb;
        }
    const int dd = lane;               // V^T row = d
    char* vbase = outPk + (size_t)(rowbase + dd) * kRowB + 6144 + hh * 256 + 128;
#pragma unroll
    for (int kgx = 0; kgx < 8; ++kgx) {
      const u16x4 a0 = *(const u16x4*)&ldsT[dd * 68 + kgx * 8];
      const u16x4 a1 = *(const u16x4*)&ldsT[dd * 68 + kgx * 8 + 4];
      char* dst = vbase + ((kgx ^ (dd & 7)) << 4);
      *(u16x4*)dst = a0;
      *(u16x4*)(dst + 8) = a1;
    }
  }
}

// ---------------------------------------------------------------------------
// Thin GEMM for out-projection (round-17 proven): 64x128 tile, depth-2
// pipelined, LDS group-XOR swizzle. Full 2-term (o-lo matters here).
// ---------------------------------------------------------------------------
__global__ __launch_bounds__(256, 2)
void gemm_thin(const u16* __restrict__ Ahg, const u16* __restrict__ Alg,
               const u16* __restrict__ Bhg,
               const float* __restrict__ bias, float* __restrict__ C,
               int M, int N, int K) {
  __shared__ __align__(16) u16 smem[16384];   // 2 x (Ah 2048 | Al 2048 | B 4096)
  const int nwg = gridDim.x;
  const int lid = xcd_swz(blockIdx.x, nwg);
  const int nTiles = N >> 7;
  const int m0 = (lid / nTiles) << 6;
  const int n0 = (lid % nTiles) << 7;

  const int tid  = threadIdx.x;
  const int wave = tid >> 6;
  const int lane = tid & 63;
  const int l15  = lane & 15;
  const int khf  = lane >> 4;

  const int rr = lane >> 2;
  const int gg = lane & 3;
  const int gsw = gg ^ ((rr >> 1) & 3);
  const int kg  = khf ^ ((l15 >> 1) & 3);

  const size_t aOff  = (size_t)(m0 + wave * 16 + rr) * K + gsw * 8;
  const size_t bOff0 = (size_t)(n0 + (2 * wave) * 16 + rr) * K + gsw * 8;
  const size_t bOff1 = (size_t)(n0 + (2 * wave + 1) * 16 + rr) * K + gsw * 8;

  auto STAGE = [&](int p, int k0) {
    u16* base = smem + p * 8192;
    glds16(Ahg + aOff + k0,  base + (wave * 16) * 32);
    glds16(Alg + aOff + k0,  base + 2048 + (wave * 16) * 32);
    glds16(Bhg + bOff0 + k0, base + 4096 + (2 * wave * 16) * 32);
    glds16(Bhg + bOff1 + k0, base + 4096 + ((2 * wave + 1) * 16) * 32);
  };

  f32x4 acc[4][2];
#pragma unroll
  for (int i = 0; i < 4; ++i)
#pragma unroll
    for (int j = 0; j < 2; ++j) acc[i][j] = (f32x4){0.f, 0.f, 0.f, 0.f};

  auto COMPUTE = [&](int p) {
    u16* base = smem + p * 8192;
    bf16x8 fah[4], fal[4], fbh[2];
#pragma unroll
    for (int f = 0; f < 4; ++f) {
      fah[f] = *(const bf16x8*)&base[(f * 16 + l15) * 32 + kg * 8];
      fal[f] = *(const bf16x8*)&base[2048 + (f * 16 + l15) * 32 + kg * 8];
    }
#pragma unroll
    for (int f = 0; f < 2; ++f)
      fbh[f] = *(const bf16x8*)&base[4096 + (wave * 32 + f * 16 + l15) * 32 + kg * 8];
#pragma unroll
    for (int mi = 0; mi < 4; ++mi)
#pragma unroll
      for (int ni = 0; ni < 2; ++ni)
        acc[mi][ni] = __builtin_amdgcn_mfma_f32_16x16x32_bf16(fah[mi], fbh[ni], acc[mi][ni], 0, 0, 0);
#pragma unroll
    for (int mi = 0; mi < 4; ++mi)
#pragma unroll
      for (int ni = 0; ni < 2; ++ni)
        acc[mi][ni] = __builtin_amdgcn_mfma_f32_16x16x32_bf16(fal[mi], fbh[ni], acc[mi][ni], 0, 0, 0);
  };

  STAGE(0, 0);
  STAGE(1, 32);
  int cur = 0;

  for (int k0 = 0; k0 < K - 32; k0 += 32) {
    asm volatile("s_waitcnt vmcnt(4)" ::: "memory");
    __builtin_amdgcn_sched_barrier(0);
    __builtin_amdgcn_s_barrier();

    COMPUTE(cur);

    __builtin_amdgcn_sched_barrier(0);
    asm volatile("s_waitcnt lgkmcnt(0)" ::: "memory");
    __builtin_amdgcn_s_barrier();
    if (k0 + 64 < K) STAGE(cur, k0 + 64);
    cur ^= 1;
  }

  asm volatile("s_waitcnt vmcnt(0)" ::: "memory");
  __builtin_amdgcn_sched_barrier(0);
  __builtin_amdgcn_s_barrier();
  COMPUTE(cur);

#pragma unroll
  for (int ni = 0; ni < 2; ++ni) {
    const int col = n0 + wave * 32 + ni * 16 + l15;
    const float bv = bias[col];
#pragma unroll
    for (int mi = 0; mi < 4; ++mi) {
      const int rbase = m0 + mi * 16 + khf * 4;
#pragma unroll
      for (int r = 0; r < 4; ++r)
        C[(size_t)(rbase + r) * N + col] = acc[mi][ni][r] + bv;
    }
  }
}

// ---------------------------------------------------------------------------
// Windowed attention + fused CLS partials (round-22 proven). Grid = 960.
// Pure bf16 QK^T; 8 glds/wave/tile; LDS 16.9 KB.
// ---------------------------------------------------------------------------
__global__ __launch_bounds__(128)
void attn_win_mfma(const char* __restrict__ qkvB,
                   u16* __restrict__ oh, u16* __restrict__ ol,
                   float* __restrict__ part) {
  __shared__ __align__(16) u16 sm[8448];   // 16.9 KB
  __shared__ float ls[2][64];

  const int idx  = xcd_swz(blockIdx.x, gridDim.x);
  const int tid  = threadIdx.x;
  const int w    = tid >> 6;           // 0..1
  const int lane = tid & 63;

  if (idx >= 768) {
    // ================= CLS partial (one 256-key chunk per wave) ============
    const int chunk = (idx - 768) * 2 + w;      // 0..383
    const int p = chunk & (kClsSplit - 1);
    const int h = (chunk >> 4) % kH;
    const int b = chunk / (kClsSplit * kH);
    const int hOff = h * 256;
    const int keysPer = kS / kClsSplit;         // 256
    float* obuf = (float*)sm + w * 2112;        // [64][33] per wave (8.4 KB)

    float q[64];
    {
      const char* qp = qkvB + (size_t)(b * kS) * kRowB + hOff;
#pragma unroll
      for (int g = 0; g < 8; ++g) {
        const u16x8v hv = *(const u16x8v*)(qp + (g << 4));
        const u16x8v lv = *(const u16x8v*)(qp + 128 + (g << 4));
#pragma unroll
        for (int j = 0; j < 8; ++j) q[g * 8 + j] = bf2f(hv[j]) + bf2f(lv[j]);
      }
    }

    float oacc[64] = {};
    float l = 0.f;
    for (int i = 0; i < keysPer / 64; ++i) {
      const int sk = p * keysPer + i * 64 + lane;
      const char* rp = qkvB + (size_t)(b * kS + sk) * kRowB;
      const int swz = sk & 7;
      float dp = 0.f;
#pragma unroll
      for (int g = 0; g < 8; ++g) {
        const char* kp = rp + 3072 + hOff + ((g ^ swz) << 4);
        const u16x8v kh = *(const u16x8v*)kp;
        const u16x8v kl = *(const u16x8v*)(kp + 128);
#pragma unroll
        for (int j = 0; j < 8; ++j)
          dp = fmaf(q[g * 8 + j], bf2f(kh[j]) + bf2f(kl[j]), dp);
      }
      const float e = __expf(dp * kScale);
      l += e;
      const char* vp = rp + 6144 + hOff;
#pragma unroll
      for (int g = 0; g < 8; ++g) {
        const u16x8v vv = *(const u16x8v*)(vp + (g << 4));
#pragma unroll
        for (int j = 0; j < 8; ++j)
          oacc[g * 8 + j] = fmaf(e, bf2f(vv[j]), oacc[g * 8 + j]);
      }
    }

    float L = l;
#pragma unroll
    for (int off = 32; off > 0; off >>= 1) L += __shfl_xor(L, off);

    // two-pass cross-lane transpose-sum in 8.4 KB (wave-local; explicit fences)
    float sum = 0.f;
#pragma unroll
    for (int pass = 0; pass < 2; ++pass) {
#pragma unroll
      for (int d = 0; d < 32; ++d) obuf[lane * 33 + d] = oacc[pass * 32 + d];
      asm volatile("s_waitcnt lgkmcnt(0)" ::: "memory");
      __builtin_amdgcn_sched_barrier(0);
      if ((lane >> 5) == pass) {
        const int cc = lane & 31;
        for (int ln = 0; ln < 64; ++ln) sum += obuf[ln * 33 + cc];
      }
      asm volatile("s_waitcnt lgkmcnt(0)" ::: "memory");
      __builtin_amdgcn_sched_barrier(0);
    }

    float* dst = part + (size_t)chunk * 66;
    dst[lane] = sum;
    if (lane == 0) dst[64] = L;
    return;
  }

  // ================= windowed attention (pure bf16 QK^T) ==================
  u16* KsH = sm;
  u16* VsT = sm + 4096;

  const int half = idx & 1;
  const int c = (idx >> 1) % kC;
  const int h = ((idx >> 1) / kC) % kH;
  const int b = idx / (2 * kC * kH);
  const int l31  = lane & 31;
  const int h5   = lane >> 5;
  const int hOff = h * 256;
  const int qbase = c * kChunk + half * 128 + w * 64;

  bf16x8 Qh[2][4];
#pragma unroll
  for (int ti = 0; ti < 2; ++ti) {
    const size_t grow = (size_t)(b * kS + qbase + ti * 32 + l31);
#pragma unroll
    for (int ksl = 0; ksl < 4; ++ksl) {
      const char* p = qkvB + grow * kRowB + hOff + ((ksl * 2 + h5) << 4);
      Qh[ti][ksl] = *(const bf16x8*)p;
    }
  }

  f32x16 Oacc[2][2];
#pragma unroll
  for (int a = 0; a < 2; ++a)
#pragma unroll
    for (int d = 0; d < 2; ++d)
#pragma unroll
      for (int i = 0; i < 16; ++i) Oacc[a][d][i] = 0.f;
  float lsA[2] = {0.f, 0.f};

  const int clo = (c > 0) ? c - 1 : 0;
  const int chi = (c < kC - 1) ? c + 1 : kC - 1;
  const int nwin = (chi - clo + 1) * 4;
  const int ntiles = nwin + ((clo != 0) ? 1 : 0);

  U32x4 pa[2][4];

  for (int tt = 0; tt < ntiles; ++tt) {
    const bool isCls = (tt >= nwin);
    const int srow = isCls ? 0 : (clo * kChunk + tt * 64);

    __syncthreads();
#pragma unroll
    for (int j = 0; j < 4; ++j) {
      const int cb = w * 256 + j * 64;     // wave-uniform LDS chunk base
      const int ch = cb + lane;
      const size_t gr = (size_t)(b * kS + srow + (ch >> 3)) * kRowB + ((ch & 7) << 4);
      glds16(qkvB + gr + 3072 + hOff,       &KsH[cb * 8]);
      glds16(qkvB + gr + 6144 + hOff + 128, &VsT[cb * 8]);
    }
    __syncthreads();

#pragma unroll
    for (int kt = 0; kt < 2; ++kt) {
      bf16x8 KH[4];
      const int krow = kt * 32 + l31;
#pragma unroll
      for (int ksl = 0; ksl < 4; ++ksl) {
        const int gg = (((ksl * 2 + h5) ^ (krow & 7)) << 3);
        KH[ksl] = *(const bf16x8*)&KsH[krow * 64 + gg];
      }
#pragma unroll
      for (int ti = 0; ti < 2; ++ti) {
        f32x16 S;
#pragma unroll
        for (int i = 0; i < 16; ++i) S[i] = 0.f;
        __builtin_amdgcn_s_setprio(1);
#pragma unroll
        for (int ksl = 0; ksl < 4; ++ksl)
          S = __builtin_amdgcn_mfma_f32_32x32x16_bf16(KH[ksl], Qh[ti][ksl], S, 0, 0, 0);
        __builtin_amdgcn_s_setprio(0);
        unsigned int wpk[4][2], sw[4][2];
        float lacc = 0.f;
#pragma unroll
        for (int m = 0; m < 4; ++m) {
          float e[4];
#pragma unroll
          for (int r = 0; r < 4; ++r) {
            float ev = __expf(S[4 * m + r] * kScale);
            if (isCls && !(kt == 0 && m == 0 && r == 0 && h5 == 0)) ev = 0.f;
            e[r] = ev;
          }
          lacc += (e[0] + e[1]) + (e[2] + e[3]);
          wpk[m][0] = pkbf(e[0], e[1]);
          wpk[m][1] = pkbf(e[2], e[3]);
        }
        lsA[ti] += lacc;
#pragma unroll
        for (int m = 0; m < 4; ++m) {
          sw[m][0] = __shfl_xor(wpk[m][0], 32);
          sw[m][1] = __shfl_xor(wpk[m][1], 32);
        }
#pragma unroll
        for (int jj = 0; jj < 2; ++jj) {
          const int m0 = 2 * jj, m1 = 2 * jj + 1;
          U32x4& P = pa[ti][kt * 2 + jj];
          P.u[0] = h5 ? sw[m1][0]  : wpk[m0][0];
          P.u[1] = h5 ? sw[m1][1]  : wpk[m0][1];
          P.u[2] = h5 ? wpk[m1][0] : sw[m0][0];
          P.u[3] = h5 ? wpk[m1][1] : sw[m0][1];
        }
      }
    }

    __builtin_amdgcn_s_setprio(1);
#pragma unroll
    for (int sl = 0; sl < 4; ++sl) {
#pragma unroll
      for (int dt = 0; dt < 2; ++dt) {
        const int vrow = dt * 32 + l31;
        const bf16x8 vb =
            *(const bf16x8*)&VsT[vrow * 64 + ((((sl * 2 + h5) ^ (vrow & 7))) << 3)];
        Oacc[0][dt] = __builtin_amdgcn_mfma_f32_32x32x16_bf16(pa[0][sl].v, vb, Oacc[0][dt], 0, 0, 0);
        Oacc[1][dt] = __builtin_amdgcn_mfma_f32_32x32x16_bf16(pa[1][sl].v, vb, Oacc[1][dt], 0, 0, 0);
      }
    }
    __builtin_amdgcn_s_setprio(0);
  }

#pragma unroll
  for (int ti = 0; ti < 2; ++ti) {
    float v = lsA[ti];
    v += __shfl_xor(v, 32);
    ls[w][ti * 32 + l31] = v;
  }

#pragma unroll
  for (int ti = 0; ti < 2; ++ti)
#pragma unroll
    for (int m = 0; m < 4; ++m)
#pragma unroll
      for (int r = 0; r < 4; ++r) {
        const int qr = r + 8 * m + 4 * h5;
        const float inv = 1.0f / ls[w][ti * 32 + qr];
        const size_t grow = (size_t)(b * kS + qbase + ti * 32 + qr);
#pragma unroll
        for (int dt = 0; dt < 2; ++dt) {
          const float val = Oacc[ti][dt][4 * m + r] * inv;
          const u16 hb = f2bf(val);
          const size_t o = grow * (size_t)kE + h * 64 + dt * 32 + l31;
          oh[o] = hb;
          ol[o] = f2bf(val - bf2f(hb));
        }
      }
}

}  // namespace

// ---------------------------------------------------------------------------
extern "C" void kernel_launch(void* const* d_in, const int* in_sizes, int n_in,
                              void* d_out, int out_size, void* d_ws, size_t ws_size,
                              hipStream_t stream) {
  const float* x      = (const float*)d_in[0];
  const int*   coords = (const int*)d_in[1];
  const float* Wqkv   = (const float*)d_in[2];
  const float* bqkv   = (const float*)d_in[3];
  const float* Wout   = (const float*)d_in[4];
  const float* bout   = (const float*)d_in[5];
  float* out = (float*)d_out;

  // Workspace (100,663,296 B):
  //   A [0 .. 75,497,472)  packed qkv [B*S][9216B] written by fused QKV GEMM
  //       epilogue (aliased post-attention: WoTh @0)
  //   B [75,497,472 .. +25,165,824)  phase1: WqTh @0; phase2: oh @0,
  //       ol @+12,582,912
  // d_out doubles as scratch (stream-ordered): xh, then cls partials,
  // then the final output overwrites it.
  char* wsb = (char*)d_ws;
  char*  qkvB = wsb;
  u16* WoTh = (u16*)wsb;
  char* rb = wsb + 75497472;
  u16* WqTh = (u16*)rb;
  u16* oh   = (u16*)rb;
  u16* ol   = (u16*)(rb + 12582912);
  u16* xh   = (u16*)d_out;
  float* clsPart = out;

  const int M = kB * kS;  // 8192

  // 1. prep: x -> bf16 hi (scratch in d_out) + transpose+bf16 W_qkv
  prep<<<3504, 256, 0, stream>>>(x, xh, Wqkv, WqTh);

  // 2. QKV projection (pure-bf16, 4-glds pipeline) with fused epilogue
  {
    const int nwg = (kQKV / 128) * (M / 128);   // 1152, %8==0
    gemm_qkv<<<nwg, 256, 0, stream>>>(xh, WqTh, bqkv, qkvB, coords, M, kQKV, kE);
  }

  // 3. Windowed attention (bf16 QK^T) + fused CLS partials -> oh/ol, clsPart
  attn_win_mfma<<<960, 128, 0, stream>>>(qkvB, oh, ol, clsPart);

  // 4. tail: transpose+bf16 W_out (dead qkv space) + CLS combine
  wsplit_comb<<<168, 256, 0, stream>>>(Wout, WoTh, clsPart, oh, ol);

  // 5. Output projection (thin 64x128 tiles, full 2-term)
  {
    const int nwg = (kE / 128) * (M / 64);      // 768, %8==0
    gemm_thin<<<nwg, 256, 0, stream>>>(oh, ol, WoTh, bout, out, M, kE, kE);
  }
}

// Round 24
// 148.618 us; speedup vs baseline: 1.3134x; 1.0502x over previous
//
#include <hip/hip_runtime.h>

namespace {

typedef unsigned short u16;
typedef __bf16 bf16x8 __attribute__((ext_vector_type(8)));
typedef __bf16 bf16x2 __attribute__((ext_vector_type(2)));
typedef float f32x4 __attribute__((ext_vector_type(4)));
typedef float f32x16 __attribute__((ext_vector_type(16)));
typedef u16 u16x8v __attribute__((ext_vector_type(8)));
struct alignas(8) u16x4 { u16 x, y, z, w; };
union U32x4 { unsigned int u[4]; bf16x8 v; };

constexpr int kS    = 4096;
constexpr int kE    = 768;
constexpr int kH    = 12;
constexpr int kD    = 64;
constexpr int kQKV  = 2304;   // 3*E
constexpr int kChunk = 256;
constexpr int kC    = 16;     // S / CHUNK
constexpr int kB    = 2;
constexpr float kScale = 0.125f;  // 1/sqrt(64)
constexpr int kRowB = 9216;       // qkv row bytes
constexpr int kClsSplit = 16;     // key-chunks per (b,h) for CLS attention
constexpr float kL2 = 0.83048202372184058696f;  // log2(10000)/16

// ---- bf16 helpers (RNE) ---------------------------------------------------
__device__ __forceinline__ u16 f2bf(float f) {
  unsigned int u = __float_as_uint(f);
  u += 0x7FFFu + ((u >> 16) & 1u);
  return (u16)(u >> 16);
}
__device__ __forceinline__ float bf2f(u16 h) {
  return __uint_as_float(((unsigned int)h) << 16);
}
// packed pair via casts -> v_cvt_pk_bf16_f32 (RNE, same bits as f2bf here)
__device__ __forceinline__ unsigned int pkbf(float a, float b) {
  bf16x2 p;
  p[0] = (__bf16)a;
  p[1] = (__bf16)b;
  return __builtin_bit_cast(unsigned int, p);
}

// ---- XCD-aware bijective block swizzle (grid % 8 == 0) ---------------------
__device__ __forceinline__ int xcd_swz(int bid, int nwg) {
  const int cpx = nwg >> 3;
  return (bid & 7) * cpx + (bid >> 3);
}

// ---- async global->LDS, 16B per lane --------------------------------------
__device__ __forceinline__ void glds16(const void* g, void* l) {
  __builtin_amdgcn_global_load_lds(
      (const __attribute__((address_space(1))) unsigned int*)g,
      (__attribute__((address_space(3))) unsigned int*)l, 16, 0, 0);
}

// ---------------------------------------------------------------------------
// wsplit body: W[K][N] fp32 -> Th[N][K] bf16 (transposed, hi only).
// ---------------------------------------------------------------------------
__device__ __forceinline__ void wsplit_body(const float* __restrict__ W,
                                            u16* __restrict__ Th, int K, int N,
                                            int bid, int t, float (*tile)[65]) {
  const int ntiles = N >> 6;
  const int n0 = (bid % ntiles) << 6;
  const int k0 = (bid / ntiles) << 6;
  const int r  = t >> 2;
  const int cs = (t & 3) << 4;
  const float* src = W + (size_t)(k0 + r) * N + n0 + cs;
#pragma unroll
  for (int i = 0; i < 4; ++i) {
    float4 v = *(const float4*)(src + 4 * i);
    tile[r][cs + 4 * i + 0] = v.x;
    tile[r][cs + 4 * i + 1] = v.y;
    tile[r][cs + 4 * i + 2] = v.z;
    tile[r][cs + 4 * i + 3] = v.w;
  }
  __syncthreads();
  u16* dh = Th + (size_t)(n0 + r) * K + k0 + cs;
#pragma unroll
  for (int i = 0; i < 4; ++i) {
    u16x4 hq;
    hq.x = f2bf(tile[cs + 4 * i + 0][r]);
    hq.y = f2bf(tile[cs + 4 * i + 1][r]);
    hq.z = f2bf(tile[cs + 4 * i + 2][r]);
    hq.w = f2bf(tile[cs + 4 * i + 3][r]);
    *(u16x4*)(dh + 4 * i) = hq;
  }
}

// ---------------------------------------------------------------------------
// prep: blocks [0,3072) = x -> bf16 hi only; blocks [3072,3504) = wsplit(W_qkv).
// ---------------------------------------------------------------------------
__global__ __launch_bounds__(256)
void prep(const float* __restrict__ x, u16* __restrict__ xh,
          const float* __restrict__ Wq, u16* __restrict__ WqTh) {
  __shared__ float tile[64][65];
  if (blockIdx.x < 3072) {
    const size_t i8 = ((size_t)blockIdx.x * 256 + threadIdx.x) * 8;
    const float4 v0 = *(const float4*)(x + i8);
    const float4 v1 = *(const float4*)(x + i8 + 4);
    const float f[8] = {v0.x, v0.y, v0.z, v0.w, v1.x, v1.y, v1.z, v1.w};
    u16x8v hv;
#pragma unroll
    for (int j = 0; j < 8; ++j) hv[j] = f2bf(f[j]);
    *(u16x8v*)(xh + i8) = hv;
  } else {
    wsplit_body(Wq, WqTh, kE, kQKV, blockIdx.x - 3072, threadIdx.x, tile);
  }
}

// ---------------------------------------------------------------------------
// tail: blocks [0,144) = wsplit(W_out); blocks [144,168) = cls combine.
// r24: cls combine writes oh only (o-lo dropped globally).
// ---------------------------------------------------------------------------
__global__ __launch_bounds__(256)
void wsplit_comb(const float* __restrict__ Wout, u16* __restrict__ WoTh,
                 const float* __restrict__ part, u16* __restrict__ oh) {
  __shared__ float tile[64][65];
  if (blockIdx.x < 144) {
    wsplit_body(Wout, WoTh, kE, kE, blockIdx.x, threadIdx.x, tile);
  } else {
    if (threadIdx.x >= 64) return;
    const int bid = blockIdx.x - 144;      // 0..23
    const int h = bid % kH;
    const int b = bid / kH;
    const int lane = threadIdx.x;
    const float* src = part + (size_t)((b * kH + h) * kClsSplit) * 66;
    float s = 0.f, L = 0.f;
#pragma unroll
    for (int p = 0; p < kClsSplit; ++p) {
      s += src[p * 66 + lane];
      L += src[p * 66 + 64];
    }
    oh[(size_t)(b * kS) * kE + h * kD + lane] = f2bf(s / L);
  }
}

// ---------------------------------------------------------------------------
// QKV GEMM (r23 proven): pure-bf16 A, 128x128 tile, depth-2 pipelined
// (4 glds/stage, vmcnt(4)), LDS group-XOR swizzle, fused rope/pack/V^T
// epilogue.
// ---------------------------------------------------------------------------
__global__ __launch_bounds__(256, 2)
void gemm_qkv(const u16* __restrict__ Ahg, const u16* __restrict__ Bhg,
              const float* __restrict__ bias, char* __restrict__ outPk,
              const int* __restrict__ coords, int M, int N, int K) {
  __shared__ __align__(16) u16 smem[17408];   // 34.8 KB (epilogue bounce)
  u16* AsH = smem;            // 2 x 4096
  u16* BsH = smem + 8192;     // 2 x 4096

  const int nwg = gridDim.x;
  const int lid = xcd_swz(blockIdx.x, nwg);
  const int nTiles = N >> 7;
  const int m0 = (lid / nTiles) << 7;
  const int n0 = (lid % nTiles) << 7;

  const int tid  = threadIdx.x;
  const int wave = tid >> 6;
  const int lane = tid & 63;
  const int l15  = lane & 15;
  const int khf  = lane >> 4;
  const int wm   = wave >> 1;
  const int wn   = wave & 1;

  const int c0 = wave * 2, c1 = wave * 2 + 1;
  const int rr = lane >> 2;
  const int gg = lane & 3;
  const int gsw = gg ^ ((rr >> 1) & 3);          // pre-swizzled source group
  const int kg  = khf ^ ((l15 >> 1) & 3);        // swizzled read slot

  const size_t bOff0 = (size_t)(n0 + c0 * 16 + rr) * K + gsw * 8;
  const size_t bOff1 = (size_t)(n0 + c1 * 16 + rr) * K + gsw * 8;
  const size_t aOff0 = (size_t)(m0 + c0 * 16 + rr) * K + gsw * 8;
  const size_t aOff1 = (size_t)(m0 + c1 * 16 + rr) * K + gsw * 8;

  auto STAGE = [&](int p, int k0) {
    glds16(Bhg + bOff0 + k0, BsH + p * 4096 + (c0 * 16) * 32);
    glds16(Bhg + bOff1 + k0, BsH + p * 4096 + (c1 * 16) * 32);
    glds16(Ahg + aOff0 + k0, AsH + p * 4096 + (c0 * 16) * 32);
    glds16(Ahg + aOff1 + k0, AsH + p * 4096 + (c1 * 16) * 32);
  };

  f32x4 acc[4][4];
#pragma unroll
  for (int i = 0; i < 4; ++i)
#pragma unroll
    for (int j = 0; j < 4; ++j) acc[i][j] = (f32x4){0.f, 0.f, 0.f, 0.f};

  auto COMPUTE = [&](int p) {
    bf16x8 fah[4], fbh[4];
#pragma unroll
    for (int f = 0; f < 4; ++f) {
      fah[f] = *(const bf16x8*)&AsH[p * 4096 + (wm * 64 + f * 16 + l15) * 32 + kg * 8];
      fbh[f] = *(const bf16x8*)&BsH[p * 4096 + (wn * 64 + f * 16 + l15) * 32 + kg * 8];
    }
#pragma unroll
    for (int mi = 0; mi < 4; ++mi)
#pragma unroll
      for (int ni = 0; ni < 4; ++ni)
        acc[mi][ni] = __builtin_amdgcn_mfma_f32_16x16x32_bf16(fah[mi], fbh[ni], acc[mi][ni], 0, 0, 0);
  };

  STAGE(0, 0);
  STAGE(1, 32);
  int cur = 0;

  for (int k0 = 0; k0 < K - 32; k0 += 32) {
    asm volatile("s_waitcnt vmcnt(4)" ::: "memory");
    __builtin_amdgcn_sched_barrier(0);
    __builtin_amdgcn_s_barrier();

    COMPUTE(cur);

    __builtin_amdgcn_sched_barrier(0);
    asm volatile("s_waitcnt lgkmcnt(0)" ::: "memory");
    __builtin_amdgcn_s_barrier();
    if (k0 + 64 < K) STAGE(cur, k0 + 64);
    cur ^= 1;
  }

  asm volatile("s_waitcnt vmcnt(0)" ::: "memory");
  __builtin_amdgcn_sched_barrier(0);
  __builtin_amdgcn_s_barrier();
  COMPUTE(cur);

  // ---- fused epilogue (r14-proven): rope/pack q,k; bf16 + V^T for v ----
  __syncthreads();   // all LDS staging reads done; smem free for bounce

  const int col64  = (n0 >> 6) + wn;   // 0..35
  const int sector = col64 / 12;       // 0=q, 1=k, 2=v
  const int hh     = col64 % 12;
  const int rowbase = m0 + wm * 64;    // 64-aligned

  if (sector < 2) {
    const int sel = sector;
#pragma unroll
    for (int mi = 0; mi < 4; ++mi)
#pragma unroll
      for (int r = 0; r < 4; ++r) {
        const int row = rowbase + mi * 16 + khf * 4 + r;
        const int bb = row >> 12;
        const int ss = row & 4095;
        float cx = 0.f, cy = 0.f;
        if (ss >= 1) {
          const size_t ci = ((size_t)bb * (kS - 1) + (ss - 1)) * 2;
          cx = (float)coords[ci]     * (1.0f / 100000.0f);
          cy = (float)coords[ci + 1] * (1.0f / 100000.0f);
        }
        const int swz = (sel == 1) ? (ss & 7) : 0;
        char* base = outPk + (size_t)row * kRowB + sel * 3072 + hh * 256;
#pragma unroll
        for (int ni = 0; ni < 4; ++ni) {
          const int d = ni * 16 + l15;
          const float v0 = acc[mi][ni][r] + bias[n0 + wn * 64 + ni * 16 + l15];
          const float pv = __shfl_xor(v0, 1);   // partner d^1 (all lanes exec)
          float nv = v0;
          if (ss >= 1) {
            const float coord = (d < 32) ? cx : cy;
            const float ang = coord * exp2f(-(float)((d >> 1) & 15) * kL2);
            const float sn = __sinf(ang), cn = __cosf(ang);
            nv = (d & 1) ? fmaf(v0, cn, pv * sn) : fmaf(v0, cn, -pv * sn);
          }
          const u16 hb = f2bf(nv);
          const u16 lb = f2bf(nv - bf2f(hb));
          const int gofs = (((d >> 3) ^ swz) << 4) + (d & 7) * 2;
          *(u16*)(base + gofs) = hb;
          *(u16*)(base + 128 + gofs) = lb;
        }
      }
  } else {
    u16* ldsT = smem + wave * 4352;    // 64 x 68 u16 per wave (8.5 KB)
#pragma unroll
    for (int mi = 0; mi < 4; ++mi)
#pragma unroll
      for (int ni = 0; ni < 4; ++ni)
#pragma unroll
        for (int r = 0; r < 4; ++r) {
          const int key = mi * 16 + khf * 4 + r;   // row within 64-group
          const int row = rowbase + key;
          const int d = ni * 16 + l15;
          const float v0 = acc[mi][ni][r] + bias[n0 + wn * 64 + ni * 16 + l15];
          const u16 hb = f2bf(v0);
          *(u16*)(outPk + (size_t)row * kRowB + 6144 + hh * 256 + d * 2) = hb;
          ldsT[d * 68 + key] = hb;
        }
    const int dd = lane;               // V^T row = d
    char* vbase = outPk + (size_t)(rowbase + dd) * kRowB + 6144 + hh * 256 + 128;
#pragma unroll
    for (int kgx = 0; kgx < 8; ++kgx) {
      const u16x4 a0 = *(const u16x4*)&ldsT[dd * 68 + kgx * 8];
      const u16x4 a1 = *(const u16x4*)&ldsT[dd * 68 + kgx * 8 + 4];
      char* dst = vbase + ((kgx ^ (dd & 7)) << 4);
      *(u16x4*)dst = a0;
      *(u16x4*)(dst + 8) = a1;
    }
  }
}

// ---------------------------------------------------------------------------
// Thin GEMM for out-projection (r24): single-term (A = oh bf16 only; the
// dropped o-lo term contributes ~7e-5 std to the fp32 output -- sub-budget).
// 64x128 tile, depth-2 pipelined (3 glds/stage, vmcnt(3)), XOR swizzle.
// ---------------------------------------------------------------------------
__global__ __launch_bounds__(256, 2)
void gemm_thin(const u16* __restrict__ Ahg, const u16* __restrict__ Bhg,
               const float* __restrict__ bias, float* __restrict__ C,
               int M, int N, int K) {
  __shared__ __align__(16) u16 smem[12288];   // 2 x (Ah 2048 | B 4096) = 24.5 KB
  const int nwg = gridDim.x;
  const int lid = xcd_swz(blockIdx.x, nwg);
  const int nTiles = N >> 7;
  const int m0 = (lid / nTiles) << 6;
  const int n0 = (lid % nTiles) << 7;

  const int tid  = threadIdx.x;
  const int wave = tid >> 6;
  const int lane = tid & 63;
  const int l15  = lane & 15;
  const int khf  = lane >> 4;

  const int rr = lane >> 2;
  const int gg = lane & 3;
  const int gsw = gg ^ ((rr >> 1) & 3);
  const int kg  = khf ^ ((l15 >> 1) & 3);

  const size_t aOff  = (size_t)(m0 + wave * 16 + rr) * K + gsw * 8;
  const size_t bOff0 = (size_t)(n0 + (2 * wave) * 16 + rr) * K + gsw * 8;
  const size_t bOff1 = (size_t)(n0 + (2 * wave + 1) * 16 + rr) * K + gsw * 8;

  auto STAGE = [&](int p, int k0) {
    u16* base = smem + p * 6144;
    glds16(Ahg + aOff + k0,  base + (wave * 16) * 32);            // Ah rows
    glds16(Bhg + bOff0 + k0, base + 2048 + (2 * wave * 16) * 32); // B rows
    glds16(Bhg + bOff1 + k0, base + 2048 + ((2 * wave + 1) * 16) * 32);
  };

  f32x4 acc[4][2];
#pragma unroll
  for (int i = 0; i < 4; ++i)
#pragma unroll
    for (int j = 0; j < 2; ++j) acc[i][j] = (f32x4){0.f, 0.f, 0.f, 0.f};

  auto COMPUTE = [&](int p) {
    u16* base = smem + p * 6144;
    bf16x8 fah[4], fbh[2];
#pragma unroll
    for (int f = 0; f < 4; ++f)
      fah[f] = *(const bf16x8*)&base[(f * 16 + l15) * 32 + kg * 8];
#pragma unroll
    for (int f = 0; f < 2; ++f)
      fbh[f] = *(const bf16x8*)&base[2048 + (wave * 32 + f * 16 + l15) * 32 + kg * 8];
#pragma unroll
    for (int mi = 0; mi < 4; ++mi)
#pragma unroll
      for (int ni = 0; ni < 2; ++ni)
        acc[mi][ni] = __builtin_amdgcn_mfma_f32_16x16x32_bf16(fah[mi], fbh[ni], acc[mi][ni], 0, 0, 0);
  };

  STAGE(0, 0);
  STAGE(1, 32);
  int cur = 0;

  for (int k0 = 0; k0 < K - 32; k0 += 32) {
    asm volatile("s_waitcnt vmcnt(3)" ::: "memory");
    __builtin_amdgcn_sched_barrier(0);
    __builtin_amdgcn_s_barrier();

    COMPUTE(cur);

    __builtin_amdgcn_sched_barrier(0);
    asm volatile("s_waitcnt lgkmcnt(0)" ::: "memory");
    __builtin_amdgcn_s_barrier();
    if (k0 + 64 < K) STAGE(cur, k0 + 64);
    cur ^= 1;
  }

  asm volatile("s_waitcnt vmcnt(0)" ::: "memory");
  __builtin_amdgcn_sched_barrier(0);
  __builtin_amdgcn_s_barrier();
  COMPUTE(cur);

#pragma unroll
  for (int ni = 0; ni < 2; ++ni) {
    const int col = n0 + wave * 32 + ni * 16 + l15;
    const float bv = bias[col];
#pragma unroll
    for (int mi = 0; mi < 4; ++mi) {
      const int rbase = m0 + mi * 16 + khf * 4;
#pragma unroll
      for (int r = 0; r < 4; ++r)
        C[(size_t)(rbase + r) * N + col] = acc[mi][ni][r] + bv;
    }
  }
}

// ---------------------------------------------------------------------------
// Windowed attention + fused CLS partials (r22/r23 proven core). Grid = 960.
// Pure bf16 QK^T; 8 glds/wave/tile; LDS 16.9 KB.
// r24: epilogue writes oh only (o-lo dropped; halves attention write traffic).
// ---------------------------------------------------------------------------
__global__ __launch_bounds__(128)
void attn_win_mfma(const char* __restrict__ qkvB,
                   u16* __restrict__ oh, float* __restrict__ part) {
  __shared__ __align__(16) u16 sm[8448];   // 16.9 KB
  __shared__ float ls[2][64];

  const int idx  = xcd_swz(blockIdx.x, gridDim.x);
  const int tid  = threadIdx.x;
  const int w    = tid >> 6;           // 0..1
  const int lane = tid & 63;

  if (idx >= 768) {
    // ================= CLS partial (one 256-key chunk per wave) ============
    const int chunk = (idx - 768) * 2 + w;      // 0..383
    const int p = chunk & (kClsSplit - 1);
    const int h = (chunk >> 4) % kH;
    const int b = chunk / (kClsSplit * kH);
    const int hOff = h * 256;
    const int keysPer = kS / kClsSplit;         // 256
    float* obuf = (float*)sm + w * 2112;        // [64][33] per wave (8.4 KB)

    float q[64];
    {
      const char* qp = qkvB + (size_t)(b * kS) * kRowB + hOff;
#pragma unroll
      for (int g = 0; g < 8; ++g) {
        const u16x8v hv = *(const u16x8v*)(qp + (g << 4));
        const u16x8v lv = *(const u16x8v*)(qp + 128 + (g << 4));
#pragma unroll
        for (int j = 0; j < 8; ++j) q[g * 8 + j] = bf2f(hv[j]) + bf2f(lv[j]);
      }
    }

    float oacc[64] = {};
    float l = 0.f;
    for (int i = 0; i < keysPer / 64; ++i) {
      const int sk = p * keysPer + i * 64 + lane;
      const char* rp = qkvB + (size_t)(b * kS + sk) * kRowB;
      const int swz = sk & 7;
      float dp = 0.f;
#pragma unroll
      for (int g = 0; g < 8; ++g) {
        const char* kp = rp + 3072 + hOff + ((g ^ swz) << 4);
        const u16x8v kh = *(const u16x8v*)kp;
        const u16x8v kl = *(const u16x8v*)(kp + 128);
#pragma unroll
        for (int j = 0; j < 8; ++j)
          dp = fmaf(q[g * 8 + j], bf2f(kh[j]) + bf2f(kl[j]), dp);
      }
      const float e = __expf(dp * kScale);
      l += e;
      const char* vp = rp + 6144 + hOff;
#pragma unroll
      for (int g = 0; g < 8; ++g) {
        const u16x8v vv = *(const u16x8v*)(vp + (g << 4));
#pragma unroll
        for (int j = 0; j < 8; ++j)
          oacc[g * 8 + j] = fmaf(e, bf2f(vv[j]), oacc[g * 8 + j]);
      }
    }

    float L = l;
#pragma unroll
    for (int off = 32; off > 0; off >>= 1) L += __shfl_xor(L, off);

    // two-pass cross-lane transpose-sum in 8.4 KB (wave-local; explicit fences)
    float sum = 0.f;
#pragma unroll
    for (int pass = 0; pass < 2; ++pass) {
#pragma unroll
      for (int d = 0; d < 32; ++d) obuf[lane * 33 + d] = oacc[pass * 32 + d];
      asm volatile("s_waitcnt lgkmcnt(0)" ::: "memory");
      __builtin_amdgcn_sched_barrier(0);
      if ((lane >> 5) == pass) {
        const int cc = lane & 31;
        for (int ln = 0; ln < 64; ++ln) sum += obuf[ln * 33 + cc];
      }
      asm volatile("s_waitcnt lgkmcnt(0)" ::: "memory");
      __builtin_amdgcn_sched_barrier(0);
    }

    float* dst = part + (size_t)chunk * 66;
    dst[lane] = sum;
    if (lane == 0) dst[64] = L;
    return;
  }

  // ================= windowed attention (pure bf16 QK^T) ==================
  u16* KsH = sm;
  u16* VsT = sm + 4096;

  const int half = idx & 1;
  const int c = (idx >> 1) % kC;
  const int h = ((idx >> 1) / kC) % kH;
  const int b = idx / (2 * kC * kH);
  const int l31  = lane & 31;
  const int h5   = lane >> 5;
  const int hOff = h * 256;
  const int qbase = c * kChunk + half * 128 + w * 64;

  bf16x8 Qh[2][4];
#pragma unroll
  for (int ti = 0; ti < 2; ++ti) {
    const size_t grow = (size_t)(b * kS + qbase + ti * 32 + l31);
#pragma unroll
    for (int ksl = 0; ksl < 4; ++ksl) {
      const char* p = qkvB + grow * kRowB + hOff + ((ksl * 2 + h5) << 4);
      Qh[ti][ksl] = *(const bf16x8*)p;
    }
  }

  f32x16 Oacc[2][2];
#pragma unroll
  for (int a = 0; a < 2; ++a)
#pragma unroll
    for (int d = 0; d < 2; ++d)
#pragma unroll
      for (int i = 0; i < 16; ++i) Oacc[a][d][i] = 0.f;
  float lsA[2] = {0.f, 0.f};

  const int clo = (c > 0) ? c - 1 : 0;
  const int chi = (c < kC - 1) ? c + 1 : kC - 1;
  const int nwin = (chi - clo + 1) * 4;
  const int ntiles = nwin + ((clo != 0) ? 1 : 0);

  U32x4 pa[2][4];

  for (int tt = 0; tt < ntiles; ++tt) {
    const bool isCls = (tt >= nwin);
    const int srow = isCls ? 0 : (clo * kChunk + tt * 64);

    __syncthreads();
#pragma unroll
    for (int j = 0; j < 4; ++j) {
      const int cb = w * 256 + j * 64;     // wave-uniform LDS chunk base
      const int ch = cb + lane;
      const size_t gr = (size_t)(b * kS + srow + (ch >> 3)) * kRowB + ((ch & 7) << 4);
      glds16(qkvB + gr + 3072 + hOff,       &KsH[cb * 8]);
      glds16(qkvB + gr + 6144 + hOff + 128, &VsT[cb * 8]);
    }
    __syncthreads();

#pragma unroll
    for (int kt = 0; kt < 2; ++kt) {
      bf16x8 KH[4];
      const int krow = kt * 32 + l31;
#pragma unroll
      for (int ksl = 0; ksl < 4; ++ksl) {
        const int gg = (((ksl * 2 + h5) ^ (krow & 7)) << 3);
        KH[ksl] = *(const bf16x8*)&KsH[krow * 64 + gg];
      }
#pragma unroll
      for (int ti = 0; ti < 2; ++ti) {
        f32x16 S;
#pragma unroll
        for (int i = 0; i < 16; ++i) S[i] = 0.f;
        __builtin_amdgcn_s_setprio(1);
#pragma unroll
        for (int ksl = 0; ksl < 4; ++ksl)
          S = __builtin_amdgcn_mfma_f32_32x32x16_bf16(KH[ksl], Qh[ti][ksl], S, 0, 0, 0);
        __builtin_amdgcn_s_setprio(0);
        unsigned int wpk[4][2], sw[4][2];
        float lacc = 0.f;
#pragma unroll
        for (int m = 0; m < 4; ++m) {
          float e[4];
#pragma unroll
          for (int r = 0; r < 4; ++r) {
            float ev = __expf(S[4 * m + r] * kScale);
            if (isCls && !(kt == 0 && m == 0 && r == 0 && h5 == 0)) ev = 0.f;
            e[r] = ev;
          }
          lacc += (e[0] + e[1]) + (e[2] + e[3]);
          wpk[m][0] = pkbf(e[0], e[1]);
          wpk[m][1] = pkbf(e[2], e[3]);
        }
        lsA[ti] += lacc;
#pragma unroll
        for (int m = 0; m < 4; ++m) {
          sw[m][0] = __shfl_xor(wpk[m][0], 32);
          sw[m][1] = __shfl_xor(wpk[m][1], 32);
        }
#pragma unroll
        for (int jj = 0; jj < 2; ++jj) {
          const int m0 = 2 * jj, m1 = 2 * jj + 1;
          U32x4& P = pa[ti][kt * 2 + jj];
          P.u[0] = h5 ? sw[m1][0]  : wpk[m0][0];
          P.u[1] = h5 ? sw[m1][1]  : wpk[m0][1];
          P.u[2] = h5 ? wpk[m1][0] : sw[m0][0];
          P.u[3] = h5 ? wpk[m1][1] : sw[m0][1];
        }
      }
    }

    __builtin_amdgcn_s_setprio(1);
#pragma unroll
    for (int sl = 0; sl < 4; ++sl) {
#pragma unroll
      for (int dt = 0; dt < 2; ++dt) {
        const int vrow = dt * 32 + l31;
        const bf16x8 vb =
            *(const bf16x8*)&VsT[vrow * 64 + ((((sl * 2 + h5) ^ (vrow & 7))) << 3)];
        Oacc[0][dt] = __builtin_amdgcn_mfma_f32_32x32x16_bf16(pa[0][sl].v, vb, Oacc[0][dt], 0, 0, 0);
        Oacc[1][dt] = __builtin_amdgcn_mfma_f32_32x32x16_bf16(pa[1][sl].v, vb, Oacc[1][dt], 0, 0, 0);
      }
    }
    __builtin_amdgcn_s_setprio(0);
  }

#pragma unroll
  for (int ti = 0; ti < 2; ++ti) {
    float v = lsA[ti];
    v += __shfl_xor(v, 32);
    ls[w][ti * 32 + l31] = v;
  }

#pragma unroll
  for (int ti = 0; ti < 2; ++ti)
#pragma unroll
    for (int m = 0; m < 4; ++m)
#pragma unroll
      for (int r = 0; r < 4; ++r) {
        const int qr = r + 8 * m + 4 * h5;
        const float inv = 1.0f / ls[w][ti * 32 + qr];
        const size_t grow = (size_t)(b * kS + qbase + ti * 32 + qr);
#pragma unroll
        for (int dt = 0; dt < 2; ++dt) {
          const float val = Oacc[ti][dt][4 * m + r] * inv;
          oh[grow * (size_t)kE + h * 64 + dt * 32 + l31] = f2bf(val);
        }
      }
}

}  // namespace

// ---------------------------------------------------------------------------
extern "C" void kernel_launch(void* const* d_in, const int* in_sizes, int n_in,
                              void* d_out, int out_size, void* d_ws, size_t ws_size,
                              hipStream_t stream) {
  const float* x      = (const float*)d_in[0];
  const int*   coords = (const int*)d_in[1];
  const float* Wqkv   = (const float*)d_in[2];
  const float* bqkv   = (const float*)d_in[3];
  const float* Wout   = (const float*)d_in[4];
  const float* bout   = (const float*)d_in[5];
  float* out = (float*)d_out;

  // Workspace (100,663,296 B):
  //   A [0 .. 75,497,472)  packed qkv [B*S][9216B] written by fused QKV GEMM
  //       epilogue (aliased post-attention: WoTh @0)
  //   B [75,497,472 .. +25,165,824)  phase1: WqTh @0; phase2: oh @0
  //       (o-lo buffer deleted in r24)
  // d_out doubles as scratch (stream-ordered): xh, then cls partials,
  // then the final output overwrites it.
  char* wsb = (char*)d_ws;
  char*  qkvB = wsb;
  u16* WoTh = (u16*)wsb;
  char* rb = wsb + 75497472;
  u16* WqTh = (u16*)rb;
  u16* oh   = (u16*)rb;
  u16* xh   = (u16*)d_out;
  float* clsPart = out;

  const int M = kB * kS;  // 8192

  // 1. prep: x -> bf16 hi (scratch in d_out) + transpose+bf16 W_qkv
  prep<<<3504, 256, 0, stream>>>(x, xh, Wqkv, WqTh);

  // 2. QKV projection (pure-bf16, 4-glds pipeline) with fused epilogue
  {
    const int nwg = (kQKV / 128) * (M / 128);   // 1152, %8==0
    gemm_qkv<<<nwg, 256, 0, stream>>>(xh, WqTh, bqkv, qkvB, coords, M, kQKV, kE);
  }

  // 3. Windowed attention (bf16 QK^T) + fused CLS partials -> oh, clsPart
  attn_win_mfma<<<960, 128, 0, stream>>>(qkvB, oh, clsPart);

  // 4. tail: transpose+bf16 W_out (dead qkv space) + CLS combine
  wsplit_comb<<<168, 256, 0, stream>>>(Wout, WoTh, clsPart, oh);

  // 5. Output projection (single-term thin 64x128 tiles)
  {
    const int nwg = (kE / 128) * (M / 64);      // 768, %8==0
    gemm_thin<<<nwg, 256, 0, stream>>>(oh, WoTh, bout, out, M, kE, kE);
  }
}